// Round 3
// baseline (835.922 us; speedup 1.0000x reference)
//
#include <hip/hip_runtime.h>
#include <hip/hip_bf16.h>

#define NN 50000
#define EE 800000
#define ELN 100000
#define ETOT (EE + NN)
#define NT 311

// ---- bucketed CSR build params ----
#define NBUCK ((NN + 127) >> 7)     // 391 buckets of 128 nodes
#define BCAP 3072                   // capacity per bucket (mean 2174, ~19 sigma margin)
#define CHUNK 8192                  // edges per k_bucket block

#define NXCD 8                      // feature slices pinned to XCDs via blockIdx%8

typedef _Float16 f16;
typedef f16 f16x8 __attribute__((ext_vector_type(8)));
typedef f16 f16x4 __attribute__((ext_vector_type(4)));
typedef f16 f16x2 __attribute__((ext_vector_type(2)));
typedef float f32x4 __attribute__((ext_vector_type(4)));

__device__ __forceinline__ float edge_alpha(float l)
{
    l = l > 0.f ? l : 0.2f * l;
    return __expf(fminf(l, 80.f));
}

// ------- fused prep + layer-1 att scores: one wave per node -------
__global__ __launch_bounds__(256) void k_prepatt(const float* __restrict__ x,
                                                 const float* __restrict__ emb,
                                                 const float* __restrict__ a1ps,
                                                 const float* __restrict__ a1pd,
                                                 f16* __restrict__ xc,
                                                 int* __restrict__ ntypes,
                                                 float* __restrict__ als,
                                                 float* __restrict__ ald)
{
    int gid = blockIdx.x * 256 + threadIdx.x;
    int n = gid >> 6, lane = gid & 63;
    if (n >= NN) return;
    int tpe = (int)x[(size_t)n * 33];
    tpe = tpe < 0 ? 0 : (tpe > NT - 1 ? NT - 1 : tpe);
    if (lane == 0) ntypes[n] = tpe;
    float v;
    if (lane < 16)      v = emb[tpe * 16 + lane];
    else if (lane < 48) v = x[(size_t)n * 33 + 1 + (lane - 16)];
    else                v = 0.f;
    f16 hv = (f16)v;
    xc[(size_t)n * 64 + lane] = hv;
    float xv = (float)hv;
    float ps[4], pd[4];
    #pragma unroll
    for (int h = 0; h < 4; ++h) {
        ps[h] = xv * a1ps[h * 64 + lane];
        pd[h] = xv * a1pd[h * 64 + lane];
    }
    #pragma unroll
    for (int off = 32; off > 0; off >>= 1) {
        #pragma unroll
        for (int h = 0; h < 4; ++h) {
            ps[h] += __shfl_xor(ps[h], off, 64);
            pd[h] += __shfl_xor(pd[h], off, 64);
        }
    }
    if (lane == 0) {
        #pragma unroll
        for (int h = 0; h < 4; ++h) {
            als[n * 4 + h] = ps[h];
            ald[n * 4 + h] = pd[h];
        }
    }
}

// ---- all weight conversions in one kernel ----
__global__ __launch_bounds__(256) void k_cvtall(const float* __restrict__ W1,
                                                const float* __restrict__ W2,
                                                const float* __restrict__ W3,
                                                const float* __restrict__ Wl1,
                                                f16* __restrict__ Wt1,
                                                f16* __restrict__ Wt2,
                                                f16* __restrict__ Wt3,
                                                f16* __restrict__ Wtl)
{
    int idx = blockIdx.x * 256 + threadIdx.x;
    if (idx < 16384) {
        int h = idx >> 12, c = (idx >> 6) & 63, k = idx & 63;
        Wt1[idx] = (k < 48) ? (f16)W1[(size_t)k * 256 + h * 64 + c] : (f16)0.f;
    } else if (idx < 81920) {
        int i = idx - 16384;
        int c = i >> 8, k = i & 255;
        Wt2[i] = (f16)W2[(size_t)k * 256 + c];
    } else if (idx < 114688) {
        int i = idx - 81920;
        int c = i >> 8, k = i & 255;
        Wt3[i] = (f16)W3[(size_t)k * 128 + c];
    } else if (idx < 131072) {
        int i = idx - 114688;
        int c = i >> 8, k = i & 255;
        Wtl[i] = (f16)Wl1[(size_t)k * 64 + c];
    }
}

// ---- fold a_src/a_dst through W1 ----
__global__ __launch_bounds__(256) void k_pre1(const float* __restrict__ W1,
                                              const float* __restrict__ as1,
                                              const float* __restrict__ ad1,
                                              float* __restrict__ a1ps,
                                              float* __restrict__ a1pd)
{
    int t = threadIdx.x;
    int h = t >> 6, k = t & 63;
    float ss = 0.f, sd = 0.f;
    if (k < 48) {
        for (int d = 0; d < 64; ++d) {
            float w = W1[(size_t)k * 256 + h * 64 + d];
            ss += w * as1[h * 64 + d];
            sd += w * ad1[h * 64 + d];
        }
    }
    a1ps[t] = ss;
    a1pd[t] = sd;
}

// ---------------- bucketed CSR build ----------------
__global__ __launch_bounds__(256) void k_bucket(const int* __restrict__ ei,
                                                int* __restrict__ bcur,
                                                int2* __restrict__ bbuf)
{
    __shared__ int hist[NBUCK];
    __shared__ int gbase[NBUCK];
    const int t = threadIdx.x;
    for (int i = t; i < NBUCK; i += 256) hist[i] = 0;
    __syncthreads();
    const int e0 = blockIdx.x * CHUNK;
    const int eend = min(e0 + CHUNK, ETOT);
    for (int e = e0 + t; e < eend; e += 256) {
        int dst = (e < EE) ? ei[EE + e] : (e - EE);
        atomicAdd(&hist[dst >> 7], 1);
    }
    __syncthreads();
    for (int i = t; i < NBUCK; i += 256) {
        int c = hist[i];
        gbase[i] = c ? atomicAdd(&bcur[i], c) : 0;
        hist[i] = 0;     // reuse as local cursor
    }
    __syncthreads();
    for (int e = e0 + t; e < eend; e += 256) {
        int src, dst;
        if (e < EE) { src = ei[e]; dst = ei[EE + e]; }
        else        { src = e - EE; dst = src; }
        int b = dst >> 7;
        int pos = gbase[b] + atomicAdd(&hist[b], 1);
        if (pos < BCAP)
            bbuf[(size_t)b * BCAP + pos] = make_int2(src, dst);
    }
}

__global__ __launch_bounds__(512) void k_bscan(const int* __restrict__ bcur,
                                               int* __restrict__ boff)
{
    __shared__ int s[512];
    int t = threadIdx.x;
    int v = (t < NBUCK) ? min(bcur[t], BCAP) : 0;
    s[t] = v;
    __syncthreads();
    #pragma unroll
    for (int off = 1; off < 512; off <<= 1) {
        int u = (t >= off) ? s[t - off] : 0;
        __syncthreads();
        s[t] += u;
        __syncthreads();
    }
    if (t < NBUCK) boff[t] = s[t] - v;
    if (t == NBUCK - 1) boff[NBUCK] = s[t];
}

// Pass B: one block per bucket. LDS counting sort by exact dst, emit rowptr
// directly, write csr fully coalesced.
__global__ __launch_bounds__(256) void k_csrb(const int* __restrict__ bcur,
                                              const int* __restrict__ boff,
                                              const int2* __restrict__ bbuf,
                                              int* __restrict__ rowptr,
                                              int* __restrict__ csr)
{
    __shared__ int nh[128];     // per-node hist -> inclusive prefix
    __shared__ int loff[128];   // per-node exclusive local offset
    __shared__ int ncur[128];
    __shared__ int ssrc[BCAP];
    const int b = blockIdx.x;
    const int t = threadIdx.x;
    const int n0 = b << 7;
    const int cnt = min(bcur[b], BCAP);
    const int base = boff[b];
    const size_t bb = (size_t)b * BCAP;
    if (t < 128) { nh[t] = 0; ncur[t] = 0; }
    __syncthreads();
    for (int i = t; i < cnt; i += 256)
        atomicAdd(&nh[bbuf[bb + i].y - n0], 1);
    __syncthreads();
    int myc = (t < 128) ? nh[t] : 0;
    #pragma unroll
    for (int off = 1; off < 128; off <<= 1) {
        int u = (t >= off && t < 128) ? nh[t - off] : 0;
        __syncthreads();
        if (t < 128) nh[t] += u;
        __syncthreads();
    }
    if (t < 128) {
        int ex = nh[t] - myc;
        loff[t] = ex;
        int n = n0 + t;
        if (n < NN) rowptr[n] = base + ex;
    }
    __syncthreads();
    for (int i = t; i < cnt; i += 256) {
        int2 p = bbuf[bb + i];
        int ln = p.y - n0;
        int pos = loff[ln] + atomicAdd(&ncur[ln], 1);
        ssrc[pos] = p.x;
    }
    __syncthreads();
    for (int i = t; i < cnt; i += 256)
        csr[base + i] = ssrc[i];
    if (b == 0 && t == 0) rowptr[NN] = boff[NBUCK];
}

// ------------- MFMA f16 GEMM, optional fused attention-score partials -------------
template<int K, int CN, int H>
__global__ __launch_bounds__(256) void k_gemmh(const f16* __restrict__ A,
                                               const f16* __restrict__ Wt,
                                               f16* __restrict__ O,
                                               int nrows,
                                               const float* __restrict__ asrc,
                                               const float* __restrict__ adst,
                                               float* __restrict__ als,
                                               float* __restrict__ ald)
{
    constexpr int LDA = 40;
    __shared__ f16 As[64 * LDA];
    __shared__ f16 Bs[64 * LDA];
    const int t = threadIdx.x;
    const int w = t >> 6;
    const int lane = t & 63;
    const int m = lane & 15;
    const int quad = lane >> 4;
    const int row0 = blockIdx.x * 64;
    const int col0 = blockIdx.y * 64;
    const int r_st = t >> 2;
    const int seg  = (t & 3) * 8;
    f32x4 acc[4] = {{0.f,0.f,0.f,0.f},{0.f,0.f,0.f,0.f},{0.f,0.f,0.f,0.f},{0.f,0.f,0.f,0.f}};
    for (int k0 = 0; k0 < K; k0 += 32) {
        int gr = row0 + r_st;
        f16x8 av = {0,0,0,0,0,0,0,0};
        if (gr < nrows) av = *(const f16x8*)&A[(size_t)gr * K + k0 + seg];
        *(f16x8*)&As[r_st * LDA + seg] = av;
        f16x8 bv = *(const f16x8*)&Wt[(size_t)(col0 + r_st) * K + k0 + seg];
        *(f16x8*)&Bs[r_st * LDA + seg] = bv;
        __syncthreads();
        f16x8 af = *(const f16x8*)&As[(w * 16 + m) * LDA + quad * 8];
        #pragma unroll
        for (int g = 0; g < 4; ++g) {
            f16x8 bf = *(const f16x8*)&Bs[(g * 16 + m) * LDA + quad * 8];
            acc[g] = __builtin_amdgcn_mfma_f32_16x16x32_f16(af, bf, acc[g], 0, 0, 0);
        }
        __syncthreads();
    }
    #pragma unroll
    for (int g = 0; g < 4; ++g) {
        #pragma unroll
        for (int reg = 0; reg < 4; ++reg) {
            int gr = row0 + w * 16 + quad * 4 + reg;
            int gc = col0 + g * 16 + m;
            if (gr < nrows) O[(size_t)gr * CN + gc] = (f16)acc[g][reg];
        }
    }
    if constexpr (H > 0) {
        constexpr int D = CN / H;
        const int head = col0 / D;
        float ps[4] = {}, pd[4] = {};
        #pragma unroll
        for (int g = 0; g < 4; ++g) {
            int col = col0 + g * 16 + m;
            float a_s = asrc[col], a_d = adst[col];
            #pragma unroll
            for (int reg = 0; reg < 4; ++reg) {
                ps[reg] += acc[g][reg] * a_s;
                pd[reg] += acc[g][reg] * a_d;
            }
        }
        #pragma unroll
        for (int off = 1; off < 16; off <<= 1) {
            #pragma unroll
            for (int reg = 0; reg < 4; ++reg) {
                ps[reg] += __shfl_xor(ps[reg], off, 64);
                pd[reg] += __shfl_xor(pd[reg], off, 64);
            }
        }
        if (m == 0) {
            #pragma unroll
            for (int reg = 0; reg < 4; ++reg) {
                int gr = row0 + w * 16 + quad * 4 + reg;
                if (gr < nrows) {
                    atomicAdd(&als[gr * H + head], ps[reg]);
                    atomicAdd(&ald[gr * H + head], pd[reg]);
                }
            }
        }
    }
}

// ----- layer-1 per-head GEMM with fused bias+ELU -----
__global__ __launch_bounds__(256) void k_gemm1h(const f16* __restrict__ A,
                                                const f16* __restrict__ Wt1,
                                                const float* __restrict__ bias,
                                                f16* __restrict__ O,
                                                int nrows)
{
    constexpr int LDA = 40;
    __shared__ f16 As[64 * LDA];
    __shared__ f16 Bs[64 * LDA];
    const int t = threadIdx.x;
    const int w = t >> 6;
    const int lane = t & 63;
    const int m = lane & 15;
    const int quad = lane >> 4;
    const int row0 = blockIdx.x * 64;
    const int head = blockIdx.y;
    const int r_st = t >> 2;
    const int seg  = (t & 3) * 8;
    f32x4 acc[4] = {{0.f,0.f,0.f,0.f},{0.f,0.f,0.f,0.f},{0.f,0.f,0.f,0.f},{0.f,0.f,0.f,0.f}};
    for (int k0 = 0; k0 < 64; k0 += 32) {
        int gr = row0 + r_st;
        f16x8 av = {0,0,0,0,0,0,0,0};
        if (gr < nrows) av = *(const f16x8*)&A[(size_t)gr * 256 + head * 64 + k0 + seg];
        *(f16x8*)&As[r_st * LDA + seg] = av;
        f16x8 bv = *(const f16x8*)&Wt1[(size_t)head * 4096 + (size_t)r_st * 64 + k0 + seg];
        *(f16x8*)&Bs[r_st * LDA + seg] = bv;
        __syncthreads();
        f16x8 af = *(const f16x8*)&As[(w * 16 + m) * LDA + quad * 8];
        #pragma unroll
        for (int g = 0; g < 4; ++g) {
            f16x8 bf = *(const f16x8*)&Bs[(g * 16 + m) * LDA + quad * 8];
            acc[g] = __builtin_amdgcn_mfma_f32_16x16x32_f16(af, bf, acc[g], 0, 0, 0);
        }
        __syncthreads();
    }
    #pragma unroll
    for (int g = 0; g < 4; ++g) {
        #pragma unroll
        for (int reg = 0; reg < 4; ++reg) {
            int gr = row0 + w * 16 + quad * 4 + reg;
            int col = head * 64 + g * 16 + m;
            if (gr < nrows) {
                float v = acc[g][reg] + bias[col];
                v = v > 0.f ? v : (__expf(v) - 1.f);
                O[(size_t)gr * 256 + col] = (f16)v;
            }
        }
    }
}

// ======= XCD-sliced aggregation kernels =======
// slice = blockIdx.x % 8 -> dispatched round-robin, so each XCD's L2 caches
// only its 1/8 feature-column slice of the gather table (fits 4 MiB).
// csr is streamed nontemporal; z/xagg stores nontemporal (protect h-slice).

// ------- layer-1 aggregate over xc: slice=8 feats, 16 edge-parities x 4 lanes -------
__global__ __launch_bounds__(256) void k_aggxs(const int* __restrict__ rowptr,
                                               const int* __restrict__ csr,
                                               const float* __restrict__ als,  // [n][4]
                                               const float* __restrict__ ald,  // [n][4]
                                               const f16* __restrict__ xc,
                                               f16* __restrict__ xagg)
{
    int b = blockIdx.x;
    int slice = b & (NXCD - 1);
    int ng = b >> 3;
    int t = threadIdx.x;
    int n = ng * 4 + (t >> 6);
    if (n >= NN) return;
    int lane = t & 63;
    int p  = lane >> 2;            // 16 edge parities
    int fl = lane & 3;             // 4 feature lanes
    int cb = slice * 8 + fl * 2;   // 2 feats per lane (f16x2)
    int r0 = rowptr[n], r1 = rowptr[n + 1];
    float4 dl = *(const float4*)&ald[(size_t)n * 4];
    float a0[2] = {}, a1[2] = {}, a2[2] = {}, a3[2] = {};
    float d0 = 0.f, d1 = 0.f, d2 = 0.f, d3 = 0.f;
    int i = r0;
    for (; i + 16 <= r1; i += 16) {
        int s0 = __builtin_nontemporal_load(&csr[i + p]);
        f16x2 xv = *(const f16x2*)&xc[(size_t)s0 * 64 + cb];
        float4 A0 = *(const float4*)&als[(size_t)s0 * 4];
        float ex = edge_alpha(A0.x + dl.x);
        float ey = edge_alpha(A0.y + dl.y);
        float ez = edge_alpha(A0.z + dl.z);
        float ew = edge_alpha(A0.w + dl.w);
        d0 += ex; d1 += ey; d2 += ez; d3 += ew;
        #pragma unroll
        for (int j = 0; j < 2; ++j) {
            float v0 = (float)xv[j];
            a0[j] += ex * v0; a1[j] += ey * v0;
            a2[j] += ez * v0; a3[j] += ew * v0;
        }
    }
    for (; i < r1; i += 16) {
        int ii = i + p;
        bool v = ii < r1;
        int s0 = __builtin_nontemporal_load(&csr[v ? ii : r0]);
        f16x2 xv = *(const f16x2*)&xc[(size_t)s0 * 64 + cb];
        float4 A0 = *(const float4*)&als[(size_t)s0 * 4];
        float ex = v ? edge_alpha(A0.x + dl.x) : 0.f;
        float ey = v ? edge_alpha(A0.y + dl.y) : 0.f;
        float ez = v ? edge_alpha(A0.z + dl.z) : 0.f;
        float ew = v ? edge_alpha(A0.w + dl.w) : 0.f;
        d0 += ex; d1 += ey; d2 += ez; d3 += ew;
        #pragma unroll
        for (int j = 0; j < 2; ++j) {
            float v0 = (float)xv[j];
            a0[j] += ex * v0; a1[j] += ey * v0;
            a2[j] += ez * v0; a3[j] += ew * v0;
        }
    }
    #pragma unroll
    for (int off = 4; off < 64; off <<= 1) {
        #pragma unroll
        for (int j = 0; j < 2; ++j) {
            a0[j] += __shfl_xor(a0[j], off, 64);
            a1[j] += __shfl_xor(a1[j], off, 64);
            a2[j] += __shfl_xor(a2[j], off, 64);
            a3[j] += __shfl_xor(a3[j], off, 64);
        }
        d0 += __shfl_xor(d0, off, 64);
        d1 += __shfl_xor(d1, off, 64);
        d2 += __shfl_xor(d2, off, 64);
        d3 += __shfl_xor(d3, off, 64);
    }
    if (p == 0) {
        float i0 = 1.f / d0, i1 = 1.f / d1, i2 = 1.f / d2, i3 = 1.f / d3;
        size_t base = (size_t)n * 256 + cb;
        f16x2 o0 = {(f16)(a0[0] * i0), (f16)(a0[1] * i0)};
        f16x2 o1 = {(f16)(a1[0] * i1), (f16)(a1[1] * i1)};
        f16x2 o2 = {(f16)(a2[0] * i2), (f16)(a2[1] * i2)};
        f16x2 o3 = {(f16)(a3[0] * i3), (f16)(a3[1] * i3)};
        __builtin_nontemporal_store(o0, (f16x2*)&xagg[base]);
        __builtin_nontemporal_store(o1, (f16x2*)&xagg[base + 64]);
        __builtin_nontemporal_store(o2, (f16x2*)&xagg[base + 128]);
        __builtin_nontemporal_store(o3, (f16x2*)&xagg[base + 192]);
    }
}

// ------- layer-2 aggregate: slice=32 feats, 8 edge-parities x 8 lanes (f16x4) -------
__global__ __launch_bounds__(256) void k_agg2s(const int* __restrict__ rowptr,
                                               const int* __restrict__ csr,
                                               const float* __restrict__ als,  // [n][2]
                                               const float* __restrict__ ald,  // [n][2]
                                               const f16* __restrict__ h,
                                               const float* __restrict__ bias,
                                               f16* __restrict__ z)
{
    int b = blockIdx.x;
    int slice = b & (NXCD - 1);
    int ng = b >> 3;
    int t = threadIdx.x;
    int n = ng * 4 + (t >> 6);
    if (n >= NN) return;
    int lane = t & 63;
    int p  = lane >> 3;             // 8 edge parities
    int fl = lane & 7;              // 8 feature lanes
    int cb = slice * 32 + fl * 4;   // 4 feats per lane (f16x4)
    int head = slice >> 2;          // wave-uniform
    int r0 = rowptr[n], r1 = rowptr[n + 1];
    float dd = ald[(size_t)n * 2 + head];
    float a[4] = {};
    float den = 0.f;
    int i = r0;
    for (; i + 16 <= r1; i += 16) {
        int s0 = __builtin_nontemporal_load(&csr[i + p]);
        int s1 = __builtin_nontemporal_load(&csr[i + 8 + p]);
        f16x4 h0 = *(const f16x4*)&h[(size_t)s0 * 256 + cb];
        f16x4 h1 = *(const f16x4*)&h[(size_t)s1 * 256 + cb];
        float e0 = edge_alpha(als[(size_t)s0 * 2 + head] + dd);
        float e1 = edge_alpha(als[(size_t)s1 * 2 + head] + dd);
        den += e0 + e1;
        #pragma unroll
        for (int j = 0; j < 4; ++j)
            a[j] += e0 * (float)h0[j] + e1 * (float)h1[j];
    }
    for (; i < r1; i += 8) {
        int ii = i + p;
        bool v = ii < r1;
        int s0 = __builtin_nontemporal_load(&csr[v ? ii : r0]);
        f16x4 h0 = *(const f16x4*)&h[(size_t)s0 * 256 + cb];
        float e0 = v ? edge_alpha(als[(size_t)s0 * 2 + head] + dd) : 0.f;
        den += e0;
        #pragma unroll
        for (int j = 0; j < 4; ++j) a[j] += e0 * (float)h0[j];
    }
    #pragma unroll
    for (int off = 8; off < 64; off <<= 1) {
        #pragma unroll
        for (int j = 0; j < 4; ++j) a[j] += __shfl_xor(a[j], off, 64);
        den += __shfl_xor(den, off, 64);
    }
    if (p == 0) {
        float inv = 1.f / den;
        f16x4 o;
        #pragma unroll
        for (int j = 0; j < 4; ++j) {
            float v = a[j] * inv + bias[cb + j];
            v = v > 0.f ? v : (__expf(v) - 1.f);
            o[j] = (f16)v;
        }
        __builtin_nontemporal_store(o, (f16x4*)&z[(size_t)n * 256 + cb]);
    }
}

// ------- layer-3 aggregate: slice=16 feats, 16 edge-parities x 4 lanes (f16x4) -------
__global__ __launch_bounds__(256) void k_agg3s(const int* __restrict__ rowptr,
                                               const int* __restrict__ csr,
                                               const float* __restrict__ als,  // [n]
                                               const float* __restrict__ ald,  // [n]
                                               const f16* __restrict__ h,
                                               const float* __restrict__ bias,
                                               f16* __restrict__ z)
{
    int b = blockIdx.x;
    int slice = b & (NXCD - 1);
    int ng = b >> 3;
    int t = threadIdx.x;
    int n = ng * 4 + (t >> 6);
    if (n >= NN) return;
    int lane = t & 63;
    int p  = lane >> 2;             // 16 edge parities
    int fl = lane & 3;              // 4 feature lanes
    int cb = slice * 16 + fl * 4;   // 4 feats per lane (f16x4)
    int r0 = rowptr[n], r1 = rowptr[n + 1];
    float dd = ald[n];
    float a[4] = {};
    float den = 0.f;
    int i = r0;
    for (; i + 16 <= r1; i += 16) {
        int s0 = __builtin_nontemporal_load(&csr[i + p]);
        f16x4 h0 = *(const f16x4*)&h[(size_t)s0 * 128 + cb];
        float e0 = edge_alpha(als[s0] + dd);
        den += e0;
        #pragma unroll
        for (int j = 0; j < 4; ++j) a[j] += e0 * (float)h0[j];
    }
    for (; i < r1; i += 16) {
        int ii = i + p;
        bool v = ii < r1;
        int s0 = __builtin_nontemporal_load(&csr[v ? ii : r0]);
        f16x4 h0 = *(const f16x4*)&h[(size_t)s0 * 128 + cb];
        float e0 = v ? edge_alpha(als[s0] + dd) : 0.f;
        den += e0;
        #pragma unroll
        for (int j = 0; j < 4; ++j) a[j] += e0 * (float)h0[j];
    }
    #pragma unroll
    for (int off = 4; off < 64; off <<= 1) {
        #pragma unroll
        for (int j = 0; j < 4; ++j) a[j] += __shfl_xor(a[j], off, 64);
        den += __shfl_xor(den, off, 64);
    }
    if (p == 0) {
        float inv = 1.f / den;
        f16x4 o;
        #pragma unroll
        for (int j = 0; j < 4; ++j)
            o[j] = (f16)(a[j] * inv + bias[cb + j]);
        __builtin_nontemporal_store(o, (f16x4*)&z[(size_t)n * 128 + cb]);
    }
}

// ---------- MFMA decoder: 64 edges/block, ef[64][256]f16 @ Wtl[64][256]^T ----------
#define DLDA 264
__global__ __launch_bounds__(256) void k_decm(const f16* __restrict__ z3,
                                              const int* __restrict__ eli,
                                              const int* __restrict__ ntypes,
                                              const f16* __restrict__ Wtl,  // [64][256]
                                              const float* __restrict__ bl1,
                                              const float* __restrict__ Wl2,
                                              const float* __restrict__ bl2,
                                              const float* __restrict__ tb,
                                              float* __restrict__ out)
{
    __shared__ f16 As[64 * DLDA];
    __shared__ int sls[64], sld[64];
    const int t = threadIdx.x;
    const int e0 = blockIdx.x * 64;
    if (t < 64) {
        int e = e0 + t;
        sls[t] = (e < ELN) ? eli[e] : 0;
        sld[t] = (e < ELN) ? eli[ELN + e] : 0;
    }
    __syncthreads();
    {
        int r = t & 63;
        int seg = t >> 6;
        int base = seg * 64;
        int node = (base < 128) ? sls[r] : sld[r];
        int zoff = base & 127;
        #pragma unroll
        for (int j = 0; j < 8; ++j) {
            f16x8 v = *(const f16x8*)&z3[(size_t)node * 128 + zoff + j * 8];
            *(f16x8*)&As[r * DLDA + base + j * 8] = v;
        }
    }
    __syncthreads();
    const int w = t >> 6;
    const int lane = t & 63;
    const int m = lane & 15;
    const int quad = lane >> 4;
    f32x4 acc[4] = {{0.f,0.f,0.f,0.f},{0.f,0.f,0.f,0.f},{0.f,0.f,0.f,0.f},{0.f,0.f,0.f,0.f}};
    for (int k0 = 0; k0 < 256; k0 += 32) {
        f16x8 af = *(const f16x8*)&As[(w * 16 + m) * DLDA + k0 + quad * 8];
        #pragma unroll
        for (int g = 0; g < 4; ++g) {
            f16x8 bf = *(const f16x8*)&Wtl[(size_t)(g * 16 + m) * 256 + k0 + quad * 8];
            acc[g] = __builtin_amdgcn_mfma_f32_16x16x32_f16(af, bf, acc[g], 0, 0, 0);
        }
    }
    float s[4] = {0.f, 0.f, 0.f, 0.f};
    #pragma unroll
    for (int g = 0; g < 4; ++g) {
        int col = g * 16 + m;
        float b = bl1[col], wv = Wl2[col];
        #pragma unroll
        for (int reg = 0; reg < 4; ++reg) {
            float hv = fmaxf(acc[g][reg] + b, 0.f);
            s[reg] += hv * wv;
        }
    }
    #pragma unroll
    for (int off = 1; off < 16; off <<= 1) {
        #pragma unroll
        for (int reg = 0; reg < 4; ++reg) s[reg] += __shfl_xor(s[reg], off, 64);
    }
    if (m == 0) {
        float b2v = bl2[0];
        #pragma unroll
        for (int reg = 0; reg < 4; ++reg) {
            int r = w * 16 + quad * 4 + reg;
            int e = e0 + r;
            if (e < ELN) {
                out[e] = s[reg] + b2v +
                         tb[(size_t)ntypes[sls[r]] * NT + ntypes[sld[r]]];
            }
        }
    }
}

// ---------------- launch ----------------
extern "C" void kernel_launch(void* const* d_in, const int* in_sizes, int n_in,
                              void* d_out, int out_size, void* d_ws, size_t ws_size,
                              hipStream_t stream)
{
    const float* x   = (const float*)d_in[0];
    const int*   ei  = (const int*)d_in[1];
    const int*   eli = (const int*)d_in[2];
    const float* emb = (const float*)d_in[3];
    const float* W1  = (const float*)d_in[4];
    const float* as1 = (const float*)d_in[5];
    const float* ad1 = (const float*)d_in[6];
    const float* b1  = (const float*)d_in[7];
    const float* W2  = (const float*)d_in[8];
    const float* as2 = (const float*)d_in[9];
    const float* ad2 = (const float*)d_in[10];
    const float* b2  = (const float*)d_in[11];
    const float* W3  = (const float*)d_in[12];
    const float* as3 = (const float*)d_in[13];
    const float* ad3 = (const float*)d_in[14];
    const float* b3  = (const float*)d_in[15];
    const float* Wl1 = (const float*)d_in[16];
    const float* bl1 = (const float*)d_in[17];
    const float* Wl2 = (const float*)d_in[18];
    const float* bl2 = (const float*)d_in[19];
    const float* tb  = (const float*)d_in[20];
    float* out = (float*)d_out;

    char* ws = (char*)d_ws;
    size_t off = 0;
    auto alloc = [&](size_t bytes) { size_t o = off; off = (off + bytes + 255) & ~(size_t)255; return o; };
    int*   ntypes = (int*)  (ws + alloc((size_t)NN * 4));
    f16*   xc16   = (f16*)  (ws + alloc((size_t)NN * 64 * 2));
    int*   rowptr = (int*)  (ws + alloc((size_t)(NN + 1) * 4));
    int*   csr    = (int*)  (ws + alloc((size_t)ETOT * 4));
    int*   bcur   = (int*)  (ws + alloc((size_t)(NBUCK + 1) * 4));
    int*   boff   = (int*)  (ws + alloc((size_t)(NBUCK + 1) * 4));
    // score buffers: [als1:4NN][ald1:4NN][als2:2NN][ald2:2NN][als3:NN][ald3:NN]
    float* scores = (float*)(ws + alloc((size_t)NN * 14 * 4));
    float* als1 = scores;
    float* ald1 = scores + (size_t)NN * 4;
    float* als2 = scores + (size_t)NN * 8;
    float* ald2 = scores + (size_t)NN * 10;
    float* als3 = scores + (size_t)NN * 12;
    float* ald3 = scores + (size_t)NN * 13;
    int2*  bbuf   = (int2*) (ws + alloc((size_t)NBUCK * BCAP * 8));
    f16*   h16    = (f16*)  (ws + alloc((size_t)NN * 256 * 2));   // also xagg
    f16*   z16    = (f16*)  (ws + alloc((size_t)NN * 256 * 2));
    f16*   Wt1    = (f16*)  (ws + alloc((size_t)4 * 64 * 64 * 2));
    f16*   Wt2    = (f16*)  (ws + alloc((size_t)256 * 256 * 2));
    f16*   Wt3    = (f16*)  (ws + alloc((size_t)128 * 256 * 2));
    f16*   Wtl    = (f16*)  (ws + alloc((size_t)64 * 256 * 2));
    float* a1ps   = (float*)(ws + alloc(256 * 4));
    float* a1pd   = (float*)(ws + alloc(256 * 4));

    hipMemsetAsync(bcur, 0, (size_t)(NBUCK + 1) * 4, stream);
    hipMemsetAsync(als2, 0, (size_t)NN * 6 * 4, stream);   // als2,ald2,als3,ald3

    const int RB   = (NN + 63) / 64;       // 782
    const int gW1  = (NN + 3) / 4;         // 1 wave/node
    const int gS   = ((NN + 3) / 4) * NXCD; // sliced agg grid: 12500 x 8 = 100000

    k_pre1<<<1, 256, 0, stream>>>(W1, as1, ad1, a1ps, a1pd);
    k_prepatt<<<gW1, 256, 0, stream>>>(x, emb, a1ps, a1pd, xc16, ntypes, als1, ald1);
    k_cvtall<<<(131072 + 255) / 256, 256, 0, stream>>>(W1, W2, W3, Wl1, Wt1, Wt2, Wt3, Wtl);

    // CSR build: bucket scatter -> bucket scan -> per-bucket counting sort
    k_bucket<<<(ETOT + CHUNK - 1) / CHUNK, 256, 0, stream>>>(ei, bcur, bbuf);
    k_bscan <<<1, 512, 0, stream>>>(bcur, boff);
    k_csrb  <<<NBUCK, 256, 0, stream>>>(bcur, boff, bbuf, rowptr, csr);

    // Layer 1 (linearity-swapped; scores from k_prepatt; alpha fused, XCD-sliced)
    k_aggxs<<<gS, 256, 0, stream>>>(rowptr, csr, als1, ald1, xc16, h16 /*xagg*/);
    k_gemm1h<<<dim3(RB, 4), 256, 0, stream>>>(h16 /*xagg*/, Wt1, b1, z16, NN);

    // Layer 2 (att fused into GEMM epilogue; alpha fused, XCD-sliced)
    k_gemmh<256, 256, 2><<<dim3(RB, 4), 256, 0, stream>>>(z16, Wt2, h16, NN, as2, ad2, als2, ald2);
    k_agg2s<<<gS, 256, 0, stream>>>(rowptr, csr, als2, ald2, h16, b2, z16);

    // Layer 3 (att fused into GEMM epilogue; alpha fused, XCD-sliced)
    k_gemmh<256, 128, 1><<<dim3(RB, 2), 256, 0, stream>>>(z16, Wt3, h16, NN, as3, ad3, als3, ald3);
    k_agg3s<<<gS, 256, 0, stream>>>(rowptr, csr, als3, ald3, h16, b3, z16);

    // Decoder (MFMA)
    k_decm<<<(ELN + 63) / 64, 256, 0, stream>>>(z16, eli, ntypes, Wtl, bl1, Wl2, bl2, tb, out);
}

// Round 4
// 417.075 us; speedup vs baseline: 2.0042x; 2.0042x over previous
//
#include <hip/hip_runtime.h>
#include <hip/hip_bf16.h>

#define NN 50000
#define EE 800000
#define ELN 100000
#define ETOT (EE + NN)
#define NT 311

// ---- bucketed CSR build params ----
#define NBUCK ((NN + 127) >> 7)     // 391 buckets of 128 nodes
#define BCAP 3072                   // capacity per bucket (mean 2174, ~19 sigma margin)
#define CHUNK 8192                  // edges per k_bucket block

typedef _Float16 f16;
typedef f16 f16x8 __attribute__((ext_vector_type(8)));
typedef f16 f16x4 __attribute__((ext_vector_type(4)));
typedef f16 f16x2 __attribute__((ext_vector_type(2)));
typedef float f32x4 __attribute__((ext_vector_type(4)));

// ------- fused prep + layer-1 att scores: one wave per node -------
__global__ __launch_bounds__(256) void k_prepatt(const float* __restrict__ x,
                                                 const float* __restrict__ emb,
                                                 const float* __restrict__ a1ps,
                                                 const float* __restrict__ a1pd,
                                                 f16* __restrict__ xc,
                                                 int* __restrict__ ntypes,
                                                 float* __restrict__ als,
                                                 float* __restrict__ ald)
{
    int gid = blockIdx.x * 256 + threadIdx.x;
    int n = gid >> 6, lane = gid & 63;
    if (n >= NN) return;
    int tpe = (int)x[(size_t)n * 33];
    tpe = tpe < 0 ? 0 : (tpe > NT - 1 ? NT - 1 : tpe);
    if (lane == 0) ntypes[n] = tpe;
    float v;
    if (lane < 16)      v = emb[tpe * 16 + lane];
    else if (lane < 48) v = x[(size_t)n * 33 + 1 + (lane - 16)];
    else                v = 0.f;
    f16 hv = (f16)v;
    xc[(size_t)n * 64 + lane] = hv;
    float xv = (float)hv;
    float ps[4], pd[4];
    #pragma unroll
    for (int h = 0; h < 4; ++h) {
        ps[h] = xv * a1ps[h * 64 + lane];
        pd[h] = xv * a1pd[h * 64 + lane];
    }
    #pragma unroll
    for (int off = 32; off > 0; off >>= 1) {
        #pragma unroll
        for (int h = 0; h < 4; ++h) {
            ps[h] += __shfl_xor(ps[h], off, 64);
            pd[h] += __shfl_xor(pd[h], off, 64);
        }
    }
    if (lane == 0) {
        #pragma unroll
        for (int h = 0; h < 4; ++h) {
            als[n * 4 + h] = ps[h];
            ald[n * 4 + h] = pd[h];
        }
    }
}

// ---- all weight conversions in one kernel ----
__global__ __launch_bounds__(256) void k_cvtall(const float* __restrict__ W1,
                                                const float* __restrict__ W2,
                                                const float* __restrict__ W3,
                                                const float* __restrict__ Wl1,
                                                f16* __restrict__ Wt1,
                                                f16* __restrict__ Wt2,
                                                f16* __restrict__ Wt3,
                                                f16* __restrict__ Wtl)
{
    int idx = blockIdx.x * 256 + threadIdx.x;
    if (idx < 16384) {
        int h = idx >> 12, c = (idx >> 6) & 63, k = idx & 63;
        Wt1[idx] = (k < 48) ? (f16)W1[(size_t)k * 256 + h * 64 + c] : (f16)0.f;
    } else if (idx < 81920) {
        int i = idx - 16384;
        int c = i >> 8, k = i & 255;
        Wt2[i] = (f16)W2[(size_t)k * 256 + c];
    } else if (idx < 114688) {
        int i = idx - 81920;
        int c = i >> 8, k = i & 255;
        Wt3[i] = (f16)W3[(size_t)k * 128 + c];
    } else if (idx < 131072) {
        int i = idx - 114688;
        int c = i >> 8, k = i & 255;
        Wtl[i] = (f16)Wl1[(size_t)k * 64 + c];
    }
}

// ---- fold a_src/a_dst through W1 ----
__global__ __launch_bounds__(256) void k_pre1(const float* __restrict__ W1,
                                              const float* __restrict__ as1,
                                              const float* __restrict__ ad1,
                                              float* __restrict__ a1ps,
                                              float* __restrict__ a1pd)
{
    int t = threadIdx.x;
    int h = t >> 6, k = t & 63;
    float ss = 0.f, sd = 0.f;
    if (k < 48) {
        for (int d = 0; d < 64; ++d) {
            float w = W1[(size_t)k * 256 + h * 64 + d];
            ss += w * as1[h * 64 + d];
            sd += w * ad1[h * 64 + d];
        }
    }
    a1ps[t] = ss;
    a1pd[t] = sd;
}

// ---------------- bucketed CSR build ----------------
__global__ __launch_bounds__(256) void k_bucket(const int* __restrict__ ei,
                                                int* __restrict__ bcur,
                                                int2* __restrict__ bbuf)
{
    __shared__ int hist[NBUCK];
    __shared__ int gbase[NBUCK];
    const int t = threadIdx.x;
    for (int i = t; i < NBUCK; i += 256) hist[i] = 0;
    __syncthreads();
    const int e0 = blockIdx.x * CHUNK;
    const int eend = min(e0 + CHUNK, ETOT);
    for (int e = e0 + t; e < eend; e += 256) {
        int dst = (e < EE) ? ei[EE + e] : (e - EE);
        atomicAdd(&hist[dst >> 7], 1);
    }
    __syncthreads();
    for (int i = t; i < NBUCK; i += 256) {
        int c = hist[i];
        gbase[i] = c ? atomicAdd(&bcur[i], c) : 0;
        hist[i] = 0;     // reuse as local cursor
    }
    __syncthreads();
    for (int e = e0 + t; e < eend; e += 256) {
        int src, dst;
        if (e < EE) { src = ei[e]; dst = ei[EE + e]; }
        else        { src = e - EE; dst = src; }
        int b = dst >> 7;
        int pos = gbase[b] + atomicAdd(&hist[b], 1);
        if (pos < BCAP)
            bbuf[(size_t)b * BCAP + pos] = make_int2(src, dst);
    }
}

__global__ __launch_bounds__(512) void k_bscan(const int* __restrict__ bcur,
                                               int* __restrict__ boff)
{
    __shared__ int s[512];
    int t = threadIdx.x;
    int v = (t < NBUCK) ? min(bcur[t], BCAP) : 0;
    s[t] = v;
    __syncthreads();
    #pragma unroll
    for (int off = 1; off < 512; off <<= 1) {
        int u = (t >= off) ? s[t - off] : 0;
        __syncthreads();
        s[t] += u;
        __syncthreads();
    }
    if (t < NBUCK) boff[t] = s[t] - v;
    if (t == NBUCK - 1) boff[NBUCK] = s[t];
}

// Pass B: one block per bucket. LDS counting sort by exact dst, emit rowptr
// directly, write csr/dstarr fully coalesced.
__global__ __launch_bounds__(256) void k_csrb(const int* __restrict__ bcur,
                                              const int* __restrict__ boff,
                                              const int2* __restrict__ bbuf,
                                              int* __restrict__ rowptr,
                                              int* __restrict__ csr,
                                              int* __restrict__ dstarr)
{
    __shared__ int nh[128];     // per-node hist -> inclusive prefix
    __shared__ int loff[128];   // per-node exclusive local offset
    __shared__ int ncur[128];
    __shared__ int ssrc[BCAP];
    __shared__ int sdst[BCAP];
    const int b = blockIdx.x;
    const int t = threadIdx.x;
    const int n0 = b << 7;
    const int cnt = min(bcur[b], BCAP);
    const int base = boff[b];
    const size_t bb = (size_t)b * BCAP;
    if (t < 128) { nh[t] = 0; ncur[t] = 0; }
    __syncthreads();
    for (int i = t; i < cnt; i += 256)
        atomicAdd(&nh[bbuf[bb + i].y - n0], 1);
    __syncthreads();
    int myc = (t < 128) ? nh[t] : 0;
    #pragma unroll
    for (int off = 1; off < 128; off <<= 1) {
        int u = (t >= off && t < 128) ? nh[t - off] : 0;
        __syncthreads();
        if (t < 128) nh[t] += u;
        __syncthreads();
    }
    if (t < 128) {
        int ex = nh[t] - myc;
        loff[t] = ex;
        int n = n0 + t;
        if (n < NN) rowptr[n] = base + ex;
    }
    __syncthreads();
    for (int i = t; i < cnt; i += 256) {
        int2 p = bbuf[bb + i];
        int ln = p.y - n0;
        int pos = loff[ln] + atomicAdd(&ncur[ln], 1);
        ssrc[pos] = p.x;
        sdst[pos] = p.y;
    }
    __syncthreads();
    for (int i = t; i < cnt; i += 256) {
        csr[base + i]    = ssrc[i];
        dstarr[base + i] = sdst[i];
    }
    if (b == 0 && t == 0) rowptr[NN] = boff[NBUCK];
}

// ------------- MFMA f16 GEMM, optional fused attention-score partials -------------
template<int K, int CN, int H>
__global__ __launch_bounds__(256) void k_gemmh(const f16* __restrict__ A,
                                               const f16* __restrict__ Wt,
                                               f16* __restrict__ O,
                                               int nrows,
                                               const float* __restrict__ asrc,
                                               const float* __restrict__ adst,
                                               float* __restrict__ als,
                                               float* __restrict__ ald)
{
    constexpr int LDA = 40;
    __shared__ f16 As[64 * LDA];
    __shared__ f16 Bs[64 * LDA];
    const int t = threadIdx.x;
    const int w = t >> 6;
    const int lane = t & 63;
    const int m = lane & 15;
    const int quad = lane >> 4;
    const int row0 = blockIdx.x * 64;
    const int col0 = blockIdx.y * 64;
    const int r_st = t >> 2;
    const int seg  = (t & 3) * 8;
    f32x4 acc[4] = {{0.f,0.f,0.f,0.f},{0.f,0.f,0.f,0.f},{0.f,0.f,0.f,0.f},{0.f,0.f,0.f,0.f}};
    for (int k0 = 0; k0 < K; k0 += 32) {
        int gr = row0 + r_st;
        f16x8 av = {0,0,0,0,0,0,0,0};
        if (gr < nrows) av = *(const f16x8*)&A[(size_t)gr * K + k0 + seg];
        *(f16x8*)&As[r_st * LDA + seg] = av;
        f16x8 bv = *(const f16x8*)&Wt[(size_t)(col0 + r_st) * K + k0 + seg];
        *(f16x8*)&Bs[r_st * LDA + seg] = bv;
        __syncthreads();
        f16x8 af = *(const f16x8*)&As[(w * 16 + m) * LDA + quad * 8];
        #pragma unroll
        for (int g = 0; g < 4; ++g) {
            f16x8 bf = *(const f16x8*)&Bs[(g * 16 + m) * LDA + quad * 8];
            acc[g] = __builtin_amdgcn_mfma_f32_16x16x32_f16(af, bf, acc[g], 0, 0, 0);
        }
        __syncthreads();
    }
    #pragma unroll
    for (int g = 0; g < 4; ++g) {
        #pragma unroll
        for (int reg = 0; reg < 4; ++reg) {
            int gr = row0 + w * 16 + quad * 4 + reg;
            int gc = col0 + g * 16 + m;
            if (gr < nrows) O[(size_t)gr * CN + gc] = (f16)acc[g][reg];
        }
    }
    if constexpr (H > 0) {
        constexpr int D = CN / H;
        const int head = col0 / D;
        float ps[4] = {}, pd[4] = {};
        #pragma unroll
        for (int g = 0; g < 4; ++g) {
            int col = col0 + g * 16 + m;
            float a_s = asrc[col], a_d = adst[col];
            #pragma unroll
            for (int reg = 0; reg < 4; ++reg) {
                ps[reg] += acc[g][reg] * a_s;
                pd[reg] += acc[g][reg] * a_d;
            }
        }
        #pragma unroll
        for (int off = 1; off < 16; off <<= 1) {
            #pragma unroll
            for (int reg = 0; reg < 4; ++reg) {
                ps[reg] += __shfl_xor(ps[reg], off, 64);
                pd[reg] += __shfl_xor(pd[reg], off, 64);
            }
        }
        if (m == 0) {
            #pragma unroll
            for (int reg = 0; reg < 4; ++reg) {
                int gr = row0 + w * 16 + quad * 4 + reg;
                if (gr < nrows) {
                    atomicAdd(&als[gr * H + head], ps[reg]);
                    atomicAdd(&ald[gr * H + head], pd[reg]);
                }
            }
        }
    }
}

// ----- layer-1 per-head GEMM with fused bias+ELU -----
__global__ __launch_bounds__(256) void k_gemm1h(const f16* __restrict__ A,
                                                const f16* __restrict__ Wt1,
                                                const float* __restrict__ bias,
                                                f16* __restrict__ O,
                                                int nrows)
{
    constexpr int LDA = 40;
    __shared__ f16 As[64 * LDA];
    __shared__ f16 Bs[64 * LDA];
    const int t = threadIdx.x;
    const int w = t >> 6;
    const int lane = t & 63;
    const int m = lane & 15;
    const int quad = lane >> 4;
    const int row0 = blockIdx.x * 64;
    const int head = blockIdx.y;
    const int r_st = t >> 2;
    const int seg  = (t & 3) * 8;
    f32x4 acc[4] = {{0.f,0.f,0.f,0.f},{0.f,0.f,0.f,0.f},{0.f,0.f,0.f,0.f},{0.f,0.f,0.f,0.f}};
    for (int k0 = 0; k0 < 64; k0 += 32) {
        int gr = row0 + r_st;
        f16x8 av = {0,0,0,0,0,0,0,0};
        if (gr < nrows) av = *(const f16x8*)&A[(size_t)gr * 256 + head * 64 + k0 + seg];
        *(f16x8*)&As[r_st * LDA + seg] = av;
        f16x8 bv = *(const f16x8*)&Wt1[(size_t)head * 4096 + (size_t)r_st * 64 + k0 + seg];
        *(f16x8*)&Bs[r_st * LDA + seg] = bv;
        __syncthreads();
        f16x8 af = *(const f16x8*)&As[(w * 16 + m) * LDA + quad * 8];
        #pragma unroll
        for (int g = 0; g < 4; ++g) {
            f16x8 bf = *(const f16x8*)&Bs[(g * 16 + m) * LDA + quad * 8];
            acc[g] = __builtin_amdgcn_mfma_f32_16x16x32_f16(af, bf, acc[g], 0, 0, 0);
        }
        __syncthreads();
    }
    #pragma unroll
    for (int g = 0; g < 4; ++g) {
        #pragma unroll
        for (int reg = 0; reg < 4; ++reg) {
            int gr = row0 + w * 16 + quad * 4 + reg;
            int col = head * 64 + g * 16 + m;
            if (gr < nrows) {
                float v = acc[g][reg] + bias[col];
                v = v > 0.f ? v : (__expf(v) - 1.f);
                O[(size_t)gr * 256 + col] = (f16)v;
            }
        }
    }
}

// -------- per-edge exp weights --------
template<int H>
__global__ __launch_bounds__(256) void k_ew(const int* __restrict__ csr,
                                            const int* __restrict__ dstarr,
                                            const float* __restrict__ als,
                                            const float* __restrict__ ald,
                                            float* __restrict__ earr)
{
    int i = blockIdx.x * 256 + threadIdx.x;
    if (i >= ETOT) return;
    int s = csr[i], d = dstarr[i];
    #pragma unroll
    for (int hh = 0; hh < H; ++hh) {
        float l = als[s * H + hh] + ald[d * H + hh];
        l = l > 0.f ? l : 0.2f * l;
        earr[(size_t)i * H + hh] = __expf(fminf(l, 80.f));
    }
}

// ------- layer-1 aggregate over xc: 4 parities x 16 lanes, f16x4 loads -------
__global__ __launch_bounds__(256) void k_aggx(const int* __restrict__ rowptr,
                                              const int* __restrict__ csr,
                                              const float* __restrict__ earr, // [i][4]
                                              const f16* __restrict__ xc,
                                              f16* __restrict__ xagg)
{
    int gid = blockIdx.x * 256 + threadIdx.x;
    int n = gid >> 6, lane = gid & 63;
    if (n >= NN) return;
    int p  = lane >> 4;        // 4 edge parities
    int fl = lane & 15;        // 16 feature lanes
    int cb = fl * 4;           // 4 feats per lane
    int r0 = rowptr[n], r1 = rowptr[n + 1];
    float a0[4] = {}, a1[4] = {}, a2[4] = {}, a3[4] = {};
    float d0 = 0.f, d1 = 0.f, d2 = 0.f, d3 = 0.f;
    int i = r0;
    for (; i + 8 <= r1; i += 8) {
        int i0 = i + p, i1 = i + 4 + p;
        int s0 = csr[i0], s1 = csr[i1];
        float4 e0 = *(const float4*)&earr[(size_t)i0 * 4];
        float4 e1 = *(const float4*)&earr[(size_t)i1 * 4];
        f16x4 x0 = *(const f16x4*)&xc[(size_t)s0 * 64 + cb];
        f16x4 x1 = *(const f16x4*)&xc[(size_t)s1 * 64 + cb];
        #pragma unroll
        for (int j = 0; j < 4; ++j) {
            float v0 = (float)x0[j], v1 = (float)x1[j];
            a0[j] += e0.x * v0 + e1.x * v1;
            a1[j] += e0.y * v0 + e1.y * v1;
            a2[j] += e0.z * v0 + e1.z * v1;
            a3[j] += e0.w * v0 + e1.w * v1;
        }
        d0 += e0.x + e1.x; d1 += e0.y + e1.y;
        d2 += e0.z + e1.z; d3 += e0.w + e1.w;
    }
    for (; i < r1; i += 4) {
        int ii = i + p;
        bool v = ii < r1;
        int s0 = csr[v ? ii : r0];
        float4 e0 = *(const float4*)&earr[(size_t)(v ? ii : r0) * 4];
        if (!v) { e0.x = 0.f; e0.y = 0.f; e0.z = 0.f; e0.w = 0.f; }
        f16x4 x0 = *(const f16x4*)&xc[(size_t)s0 * 64 + cb];
        #pragma unroll
        for (int j = 0; j < 4; ++j) {
            float v0 = (float)x0[j];
            a0[j] += e0.x * v0; a1[j] += e0.y * v0;
            a2[j] += e0.z * v0; a3[j] += e0.w * v0;
        }
        d0 += e0.x; d1 += e0.y; d2 += e0.z; d3 += e0.w;
    }
    #pragma unroll
    for (int off = 16; off < 64; off <<= 1) {
        #pragma unroll
        for (int j = 0; j < 4; ++j) {
            a0[j] += __shfl_xor(a0[j], off, 64);
            a1[j] += __shfl_xor(a1[j], off, 64);
            a2[j] += __shfl_xor(a2[j], off, 64);
            a3[j] += __shfl_xor(a3[j], off, 64);
        }
        d0 += __shfl_xor(d0, off, 64);
        d1 += __shfl_xor(d1, off, 64);
        d2 += __shfl_xor(d2, off, 64);
        d3 += __shfl_xor(d3, off, 64);
    }
    if (p == 0) {
        float i0 = 1.f / d0, i1 = 1.f / d1, i2 = 1.f / d2, i3 = 1.f / d3;
        size_t base = (size_t)n * 256 + cb;
        f16x4 o0, o1, o2, o3;
        #pragma unroll
        for (int j = 0; j < 4; ++j) {
            o0[j] = (f16)(a0[j] * i0);
            o1[j] = (f16)(a1[j] * i1);
            o2[j] = (f16)(a2[j] * i2);
            o3[j] = (f16)(a3[j] * i3);
        }
        *(f16x4*)&xagg[base]       = o0;
        *(f16x4*)&xagg[base + 64]  = o1;
        *(f16x4*)&xagg[base + 128] = o2;
        *(f16x4*)&xagg[base + 192] = o3;
    }
}

// ------- layer-2 aggregate: 32 lanes/row (f16x8), 2 edge-parities, 4x unroll -------
__global__ __launch_bounds__(256) void k_agg2f(const int* __restrict__ rowptr,
                                               const int* __restrict__ csr,
                                               const float* __restrict__ earr, // [i][2]
                                               const f16* __restrict__ h,
                                               const float* __restrict__ bias,
                                               f16* __restrict__ z)
{
    int gid = blockIdx.x * 256 + threadIdx.x;
    int n = gid >> 6, lane = gid & 63;
    if (n >= NN) return;
    int p  = lane >> 5;
    int cb = (lane & 31) * 8;
    int head = cb >> 7;
    int r0 = rowptr[n], r1 = rowptr[n + 1];
    float a[8] = {};
    float den = 0.f;
    int i = r0;
    for (; i + 8 <= r1; i += 8) {
        int i0 = i + p, i1 = i + 2 + p, i2 = i + 4 + p, i3 = i + 6 + p;
        int s0 = csr[i0], s1 = csr[i1], s2 = csr[i2], s3 = csr[i3];
        float e0 = earr[(size_t)i0 * 2 + head];
        float e1 = earr[(size_t)i1 * 2 + head];
        float e2 = earr[(size_t)i2 * 2 + head];
        float e3 = earr[(size_t)i3 * 2 + head];
        f16x8 h0 = *(const f16x8*)&h[(size_t)s0 * 256 + cb];
        f16x8 h1 = *(const f16x8*)&h[(size_t)s1 * 256 + cb];
        f16x8 h2 = *(const f16x8*)&h[(size_t)s2 * 256 + cb];
        f16x8 h3 = *(const f16x8*)&h[(size_t)s3 * 256 + cb];
        #pragma unroll
        for (int j = 0; j < 8; ++j)
            a[j] += e0 * (float)h0[j] + e1 * (float)h1[j]
                  + e2 * (float)h2[j] + e3 * (float)h3[j];
        den += e0 + e1 + e2 + e3;
    }
    for (; i < r1; i += 2) {
        int ii = i + p;
        bool v = ii < r1;
        int s0 = csr[v ? ii : r0];
        float e0 = v ? earr[(size_t)ii * 2 + head] : 0.f;
        f16x8 h0 = *(const f16x8*)&h[(size_t)s0 * 256 + cb];
        #pragma unroll
        for (int j = 0; j < 8; ++j) a[j] += e0 * (float)h0[j];
        den += e0;
    }
    #pragma unroll
    for (int j = 0; j < 8; ++j) a[j] += __shfl_xor(a[j], 32, 64);
    den += __shfl_xor(den, 32, 64);
    if (p == 0) {
        float inv = 1.f / den;
        f16x8 o;
        #pragma unroll
        for (int j = 0; j < 8; ++j) {
            float v = a[j] * inv + bias[cb + j];
            v = v > 0.f ? v : (__expf(v) - 1.f);
            o[j] = (f16)v;
        }
        *(f16x8*)&z[(size_t)n * 256 + cb] = o;
    }
}

// ------- layer-3 aggregate: 16 lanes/row (f16x8), 4 edge-parities, 2x unroll -------
__global__ __launch_bounds__(256) void k_agg3(const int* __restrict__ rowptr,
                                              const int* __restrict__ csr,
                                              const float* __restrict__ earr, // [i]
                                              const f16* __restrict__ h,
                                              const float* __restrict__ bias,
                                              f16* __restrict__ z)
{
    int gid = blockIdx.x * 256 + threadIdx.x;
    int n = gid >> 6, lane = gid & 63;
    if (n >= NN) return;
    int p  = lane >> 4;
    int cb = (lane & 15) * 8;
    int r0 = rowptr[n], r1 = rowptr[n + 1];
    float a[8] = {};
    float den = 0.f;
    int i = r0;
    for (; i + 8 <= r1; i += 8) {
        int i0 = i + p, i1 = i + 4 + p;
        int s0 = csr[i0], s1 = csr[i1];
        float e0 = earr[i0], e1 = earr[i1];
        f16x8 h0 = *(const f16x8*)&h[(size_t)s0 * 128 + cb];
        f16x8 h1 = *(const f16x8*)&h[(size_t)s1 * 128 + cb];
        #pragma unroll
        for (int j = 0; j < 8; ++j)
            a[j] += e0 * (float)h0[j] + e1 * (float)h1[j];
        den += e0 + e1;
    }
    for (; i < r1; i += 4) {
        int ii = i + p;
        bool v = ii < r1;
        int s0 = csr[v ? ii : r0];
        float e0 = v ? earr[ii] : 0.f;
        f16x8 h0 = *(const f16x8*)&h[(size_t)s0 * 128 + cb];
        #pragma unroll
        for (int j = 0; j < 8; ++j) a[j] += e0 * (float)h0[j];
        den += e0;
    }
    #pragma unroll
    for (int j = 0; j < 8; ++j) {
        a[j] += __shfl_xor(a[j], 16, 64);
        a[j] += __shfl_xor(a[j], 32, 64);
    }
    den += __shfl_xor(den, 16, 64);
    den += __shfl_xor(den, 32, 64);
    if (lane < 16) {
        float inv = 1.f / den;
        f16x8 o;
        #pragma unroll
        for (int j = 0; j < 8; ++j)
            o[j] = (f16)(a[j] * inv + bias[cb + j]);
        *(f16x8*)&z[(size_t)n * 128 + cb] = o;
    }
}

// ---------- MFMA decoder: 64 edges/block, ef[64][256]f16 @ Wtl[64][256]^T ----------
#define DLDA 264
__global__ __launch_bounds__(256) void k_decm(const f16* __restrict__ z3,
                                              const int* __restrict__ eli,
                                              const int* __restrict__ ntypes,
                                              const f16* __restrict__ Wtl,  // [64][256]
                                              const float* __restrict__ bl1,
                                              const float* __restrict__ Wl2,
                                              const float* __restrict__ bl2,
                                              const float* __restrict__ tb,
                                              float* __restrict__ out)
{
    __shared__ f16 As[64 * DLDA];
    __shared__ int sls[64], sld[64];
    const int t = threadIdx.x;
    const int e0 = blockIdx.x * 64;
    if (t < 64) {
        int e = e0 + t;
        sls[t] = (e < ELN) ? eli[e] : 0;
        sld[t] = (e < ELN) ? eli[ELN + e] : 0;
    }
    __syncthreads();
    {
        int r = t & 63;
        int seg = t >> 6;
        int base = seg * 64;
        int node = (base < 128) ? sls[r] : sld[r];
        int zoff = base & 127;
        #pragma unroll
        for (int j = 0; j < 8; ++j) {
            f16x8 v = *(const f16x8*)&z3[(size_t)node * 128 + zoff + j * 8];
            *(f16x8*)&As[r * DLDA + base + j * 8] = v;
        }
    }
    __syncthreads();
    const int w = t >> 6;
    const int lane = t & 63;
    const int m = lane & 15;
    const int quad = lane >> 4;
    f32x4 acc[4] = {{0.f,0.f,0.f,0.f},{0.f,0.f,0.f,0.f},{0.f,0.f,0.f,0.f},{0.f,0.f,0.f,0.f}};
    for (int k0 = 0; k0 < 256; k0 += 32) {
        f16x8 af = *(const f16x8*)&As[(w * 16 + m) * DLDA + k0 + quad * 8];
        #pragma unroll
        for (int g = 0; g < 4; ++g) {
            f16x8 bf = *(const f16x8*)&Wtl[(size_t)(g * 16 + m) * 256 + k0 + quad * 8];
            acc[g] = __builtin_amdgcn_mfma_f32_16x16x32_f16(af, bf, acc[g], 0, 0, 0);
        }
    }
    float s[4] = {0.f, 0.f, 0.f, 0.f};
    #pragma unroll
    for (int g = 0; g < 4; ++g) {
        int col = g * 16 + m;
        float b = bl1[col], wv = Wl2[col];
        #pragma unroll
        for (int reg = 0; reg < 4; ++reg) {
            float hv = fmaxf(acc[g][reg] + b, 0.f);
            s[reg] += hv * wv;
        }
    }
    #pragma unroll
    for (int off = 1; off < 16; off <<= 1) {
        #pragma unroll
        for (int reg = 0; reg < 4; ++reg) s[reg] += __shfl_xor(s[reg], off, 64);
    }
    if (m == 0) {
        float b2v = bl2[0];
        #pragma unroll
        for (int reg = 0; reg < 4; ++reg) {
            int r = w * 16 + quad * 4 + reg;
            int e = e0 + r;
            if (e < ELN) {
                out[e] = s[reg] + b2v +
                         tb[(size_t)ntypes[sls[r]] * NT + ntypes[sld[r]]];
            }
        }
    }
}

// ---------------- launch ----------------
extern "C" void kernel_launch(void* const* d_in, const int* in_sizes, int n_in,
                              void* d_out, int out_size, void* d_ws, size_t ws_size,
                              hipStream_t stream)
{
    const float* x   = (const float*)d_in[0];
    const int*   ei  = (const int*)d_in[1];
    const int*   eli = (const int*)d_in[2];
    const float* emb = (const float*)d_in[3];
    const float* W1  = (const float*)d_in[4];
    const float* as1 = (const float*)d_in[5];
    const float* ad1 = (const float*)d_in[6];
    const float* b1  = (const float*)d_in[7];
    const float* W2  = (const float*)d_in[8];
    const float* as2 = (const float*)d_in[9];
    const float* ad2 = (const float*)d_in[10];
    const float* b2  = (const float*)d_in[11];
    const float* W3  = (const float*)d_in[12];
    const float* as3 = (const float*)d_in[13];
    const float* ad3 = (const float*)d_in[14];
    const float* b3  = (const float*)d_in[15];
    const float* Wl1 = (const float*)d_in[16];
    const float* bl1 = (const float*)d_in[17];
    const float* Wl2 = (const float*)d_in[18];
    const float* bl2 = (const float*)d_in[19];
    const float* tb  = (const float*)d_in[20];
    float* out = (float*)d_out;

    char* ws = (char*)d_ws;
    size_t off = 0;
    auto alloc = [&](size_t bytes) { size_t o = off; off = (off + bytes + 255) & ~(size_t)255; return o; };
    int*   ntypes = (int*)  (ws + alloc((size_t)NN * 4));
    f16*   xc16   = (f16*)  (ws + alloc((size_t)NN * 64 * 2));
    int*   rowptr = (int*)  (ws + alloc((size_t)(NN + 1) * 4));
    int*   csr    = (int*)  (ws + alloc((size_t)ETOT * 4));
    int*   dstarr = (int*)  (ws + alloc((size_t)ETOT * 4));
    int*   bcur   = (int*)  (ws + alloc((size_t)(NBUCK + 1) * 4));
    int*   boff   = (int*)  (ws + alloc((size_t)(NBUCK + 1) * 4));
    // score buffers: [als1:4NN][ald1:4NN][als2:2NN][ald2:2NN][als3:NN][ald3:NN]
    float* scores = (float*)(ws + alloc((size_t)NN * 14 * 4));
    float* als1 = scores;
    float* ald1 = scores + (size_t)NN * 4;
    float* als2 = scores + (size_t)NN * 8;
    float* ald2 = scores + (size_t)NN * 10;
    float* als3 = scores + (size_t)NN * 12;
    float* ald3 = scores + (size_t)NN * 13;
    float* earr   = (float*)(ws + alloc((size_t)ETOT * 4 * 4));
    f16*   h16    = (f16*)  (ws + alloc((size_t)NN * 256 * 2));   // also xagg
    f16*   z16    = (f16*)  (ws + alloc((size_t)NN * 256 * 2));
    f16*   Wt1    = (f16*)  (ws + alloc((size_t)4 * 64 * 64 * 2));
    f16*   Wt2    = (f16*)  (ws + alloc((size_t)256 * 256 * 2));
    f16*   Wt3    = (f16*)  (ws + alloc((size_t)128 * 256 * 2));
    f16*   Wtl    = (f16*)  (ws + alloc((size_t)64 * 256 * 2));
    float* a1ps   = (float*)(ws + alloc(256 * 4));
    float* a1pd   = (float*)(ws + alloc(256 * 4));

    // bucket pair buffer (9.6 MB) aliases earr (13.6 MB): earr is first
    // written by k_ew<4>, strictly after the CSR build on this stream.
    int2* bbuf = (int2*)earr;

    hipMemsetAsync(bcur, 0, (size_t)(NBUCK + 1) * 4, stream);
    hipMemsetAsync(als2, 0, (size_t)NN * 6 * 4, stream);   // als2,ald2,als3,ald3

    const int gE   = (ETOT + 255) / 256;
    const int RB   = (NN + 63) / 64;       // 782
    const int gW1  = (NN + 3) / 4;         // 1 wave/node

    k_pre1<<<1, 256, 0, stream>>>(W1, as1, ad1, a1ps, a1pd);
    k_prepatt<<<gW1, 256, 0, stream>>>(x, emb, a1ps, a1pd, xc16, ntypes, als1, ald1);
    k_cvtall<<<(131072 + 255) / 256, 256, 0, stream>>>(W1, W2, W3, Wl1, Wt1, Wt2, Wt3, Wtl);

    // CSR build: bucket scatter -> bucket scan -> per-bucket counting sort
    k_bucket<<<(ETOT + CHUNK - 1) / CHUNK, 256, 0, stream>>>(ei, bcur, bbuf);
    k_bscan <<<1, 512, 0, stream>>>(bcur, boff);
    k_csrb  <<<NBUCK, 256, 0, stream>>>(bcur, boff, bbuf, rowptr, csr, dstarr);

    // Layer 1 (linearity-swapped; scores from k_prepatt)
    k_ew<4><<<gE, 256, 0, stream>>>(csr, dstarr, als1, ald1, earr);
    k_aggx<<<gW1, 256, 0, stream>>>(rowptr, csr, earr, xc16, h16 /*xagg*/);
    k_gemm1h<<<dim3(RB, 4), 256, 0, stream>>>(h16 /*xagg*/, Wt1, b1, z16, NN);

    // Layer 2 (att fused into GEMM epilogue; buffers pre-zeroed upfront)
    k_gemmh<256, 256, 2><<<dim3(RB, 4), 256, 0, stream>>>(z16, Wt2, h16, NN, as2, ad2, als2, ald2);
    k_ew<2><<<gE, 256, 0, stream>>>(csr, dstarr, als2, ald2, earr);
    k_agg2f<<<gW1, 256, 0, stream>>>(rowptr, csr, earr, h16, b2, z16);

    // Layer 3 (att fused into GEMM epilogue; buffers pre-zeroed upfront)
    k_gemmh<256, 128, 1><<<dim3(RB, 2), 256, 0, stream>>>(z16, Wt3, h16, NN, as3, ad3, als3, ald3);
    k_ew<1><<<gE, 256, 0, stream>>>(csr, dstarr, als3, ald3, earr);
    k_agg3<<<gW1, 256, 0, stream>>>(rowptr, csr, earr, h16, b3, z16);

    // Decoder (MFMA)
    k_decm<<<(ELN + 63) / 64, 256, 0, stream>>>(z16, eli, ntypes, Wtl, bl1, Wl2, bl2, tb, out);
}

// Round 5
// 411.076 us; speedup vs baseline: 2.0335x; 1.0146x over previous
//
#include <hip/hip_runtime.h>
#include <hip/hip_bf16.h>

#define NN 50000
#define EE 800000
#define ELN 100000
#define ETOT (EE + NN)
#define NT 311

// ---- bucketed CSR build params ----
#define NBUCK ((NN + 127) >> 7)     // 391 buckets of 128 nodes
#define BCAP 3072                   // capacity per bucket (mean 2174, ~19 sigma margin)
#define CHUNK 8192                  // edges per k_bucket block

typedef _Float16 f16;
typedef f16 f16x8 __attribute__((ext_vector_type(8)));
typedef f16 f16x4 __attribute__((ext_vector_type(4)));
typedef f16 f16x2 __attribute__((ext_vector_type(2)));
typedef float f32x4 __attribute__((ext_vector_type(4)));

// ------- fused prep + layer-1 att scores: one wave per node -------
__global__ __launch_bounds__(256) void k_prepatt(const float* __restrict__ x,
                                                 const float* __restrict__ emb,
                                                 const float* __restrict__ a1ps,
                                                 const float* __restrict__ a1pd,
                                                 f16* __restrict__ xc,
                                                 int* __restrict__ ntypes,
                                                 float* __restrict__ als,
                                                 float* __restrict__ ald)
{
    int gid = blockIdx.x * 256 + threadIdx.x;
    int n = gid >> 6, lane = gid & 63;
    if (n >= NN) return;
    int tpe = (int)x[(size_t)n * 33];
    tpe = tpe < 0 ? 0 : (tpe > NT - 1 ? NT - 1 : tpe);
    if (lane == 0) ntypes[n] = tpe;
    float v;
    if (lane < 16)      v = emb[tpe * 16 + lane];
    else if (lane < 48) v = x[(size_t)n * 33 + 1 + (lane - 16)];
    else                v = 0.f;
    f16 hv = (f16)v;
    xc[(size_t)n * 64 + lane] = hv;
    float xv = (float)hv;
    float ps[4], pd[4];
    #pragma unroll
    for (int h = 0; h < 4; ++h) {
        ps[h] = xv * a1ps[h * 64 + lane];
        pd[h] = xv * a1pd[h * 64 + lane];
    }
    #pragma unroll
    for (int off = 32; off > 0; off >>= 1) {
        #pragma unroll
        for (int h = 0; h < 4; ++h) {
            ps[h] += __shfl_xor(ps[h], off, 64);
            pd[h] += __shfl_xor(pd[h], off, 64);
        }
    }
    if (lane == 0) {
        #pragma unroll
        for (int h = 0; h < 4; ++h) {
            als[n * 4 + h] = ps[h];
            ald[n * 4 + h] = pd[h];
        }
    }
}

// ---- all weight conversions in one kernel ----
__global__ __launch_bounds__(256) void k_cvtall(const float* __restrict__ W1,
                                                const float* __restrict__ W2,
                                                const float* __restrict__ W3,
                                                const float* __restrict__ Wl1,
                                                f16* __restrict__ Wt1,
                                                f16* __restrict__ Wt2,
                                                f16* __restrict__ Wt3,
                                                f16* __restrict__ Wtl)
{
    int idx = blockIdx.x * 256 + threadIdx.x;
    if (idx < 16384) {
        int h = idx >> 12, c = (idx >> 6) & 63, k = idx & 63;
        Wt1[idx] = (k < 48) ? (f16)W1[(size_t)k * 256 + h * 64 + c] : (f16)0.f;
    } else if (idx < 81920) {
        int i = idx - 16384;
        int c = i >> 8, k = i & 255;
        Wt2[i] = (f16)W2[(size_t)k * 256 + c];
    } else if (idx < 114688) {
        int i = idx - 81920;
        int c = i >> 8, k = i & 255;
        Wt3[i] = (f16)W3[(size_t)k * 128 + c];
    } else if (idx < 131072) {
        int i = idx - 114688;
        int c = i >> 8, k = i & 255;
        Wtl[i] = (f16)Wl1[(size_t)k * 64 + c];
    }
}

// ---- fold a_src/a_dst through W1 ----
__global__ __launch_bounds__(256) void k_pre1(const float* __restrict__ W1,
                                              const float* __restrict__ as1,
                                              const float* __restrict__ ad1,
                                              float* __restrict__ a1ps,
                                              float* __restrict__ a1pd)
{
    int t = threadIdx.x;
    int h = t >> 6, k = t & 63;
    float ss = 0.f, sd = 0.f;
    if (k < 48) {
        for (int d = 0; d < 64; ++d) {
            float w = W1[(size_t)k * 256 + h * 64 + d];
            ss += w * as1[h * 64 + d];
            sd += w * ad1[h * 64 + d];
        }
    }
    a1ps[t] = ss;
    a1pd[t] = sd;
}

// ---------------- bucketed CSR build ----------------
__global__ __launch_bounds__(256) void k_bucket(const int* __restrict__ ei,
                                                int* __restrict__ bcur,
                                                int2* __restrict__ bbuf)
{
    __shared__ int hist[NBUCK];
    __shared__ int gbase[NBUCK];
    const int t = threadIdx.x;
    for (int i = t; i < NBUCK; i += 256) hist[i] = 0;
    __syncthreads();
    const int e0 = blockIdx.x * CHUNK;
    const int eend = min(e0 + CHUNK, ETOT);
    for (int e = e0 + t; e < eend; e += 256) {
        int dst = (e < EE) ? ei[EE + e] : (e - EE);
        atomicAdd(&hist[dst >> 7], 1);
    }
    __syncthreads();
    for (int i = t; i < NBUCK; i += 256) {
        int c = hist[i];
        gbase[i] = c ? atomicAdd(&bcur[i], c) : 0;
        hist[i] = 0;     // reuse as local cursor
    }
    __syncthreads();
    for (int e = e0 + t; e < eend; e += 256) {
        int src, dst;
        if (e < EE) { src = ei[e]; dst = ei[EE + e]; }
        else        { src = e - EE; dst = src; }
        int b = dst >> 7;
        int pos = gbase[b] + atomicAdd(&hist[b], 1);
        if (pos < BCAP)
            bbuf[(size_t)b * BCAP + pos] = make_int2(src, dst);
    }
}

__global__ __launch_bounds__(512) void k_bscan(const int* __restrict__ bcur,
                                               int* __restrict__ boff)
{
    __shared__ int s[512];
    int t = threadIdx.x;
    int v = (t < NBUCK) ? min(bcur[t], BCAP) : 0;
    s[t] = v;
    __syncthreads();
    #pragma unroll
    for (int off = 1; off < 512; off <<= 1) {
        int u = (t >= off) ? s[t - off] : 0;
        __syncthreads();
        s[t] += u;
        __syncthreads();
    }
    if (t < NBUCK) boff[t] = s[t] - v;
    if (t == NBUCK - 1) boff[NBUCK] = s[t];
}

// Pass B: one block per bucket. LDS counting sort by exact dst, emit rowptr
// directly, write csr/dstarr fully coalesced.
__global__ __launch_bounds__(256) void k_csrb(const int* __restrict__ bcur,
                                              const int* __restrict__ boff,
                                              const int2* __restrict__ bbuf,
                                              int* __restrict__ rowptr,
                                              int* __restrict__ csr,
                                              int* __restrict__ dstarr)
{
    __shared__ int nh[128];     // per-node hist -> inclusive prefix
    __shared__ int loff[128];   // per-node exclusive local offset
    __shared__ int ncur[128];
    __shared__ int ssrc[BCAP];
    __shared__ int sdst[BCAP];
    const int b = blockIdx.x;
    const int t = threadIdx.x;
    const int n0 = b << 7;
    const int cnt = min(bcur[b], BCAP);
    const int base = boff[b];
    const size_t bb = (size_t)b * BCAP;
    if (t < 128) { nh[t] = 0; ncur[t] = 0; }
    __syncthreads();
    for (int i = t; i < cnt; i += 256)
        atomicAdd(&nh[bbuf[bb + i].y - n0], 1);
    __syncthreads();
    int myc = (t < 128) ? nh[t] : 0;
    #pragma unroll
    for (int off = 1; off < 128; off <<= 1) {
        int u = (t >= off && t < 128) ? nh[t - off] : 0;
        __syncthreads();
        if (t < 128) nh[t] += u;
        __syncthreads();
    }
    if (t < 128) {
        int ex = nh[t] - myc;
        loff[t] = ex;
        int n = n0 + t;
        if (n < NN) rowptr[n] = base + ex;
    }
    __syncthreads();
    for (int i = t; i < cnt; i += 256) {
        int2 p = bbuf[bb + i];
        int ln = p.y - n0;
        int pos = loff[ln] + atomicAdd(&ncur[ln], 1);
        ssrc[pos] = p.x;
        sdst[pos] = p.y;
    }
    __syncthreads();
    for (int i = t; i < cnt; i += 256) {
        csr[base + i]    = ssrc[i];
        dstarr[base + i] = sdst[i];
    }
    if (b == 0 && t == 0) rowptr[NN] = boff[NBUCK];
}

// ------- MFMA f16 GEMM, 128x128 tile, optional fused attention-score partials -------
// 4 waves; wave w computes rows [w*32, w*32+32) x 128 cols. 16 MFMA per K-step
// per wave (4x the 64-tile version's barrier amortization).
template<int K, int CN, int H>
__global__ __launch_bounds__(256) void k_gemmw(const f16* __restrict__ A,
                                               const f16* __restrict__ Wt,
                                               f16* __restrict__ O,
                                               int nrows,
                                               const float* __restrict__ asrc,
                                               const float* __restrict__ adst,
                                               float* __restrict__ als,
                                               float* __restrict__ ald)
{
    constexpr int LDK = 40;
    __shared__ f16 As[128 * LDK];
    __shared__ f16 Bs[128 * LDK];
    const int t = threadIdx.x;
    const int w = t >> 6;
    const int lane = t & 63;
    const int m = lane & 15;
    const int quad = lane >> 4;
    const int row0 = blockIdx.x * 128;
    const int col0 = blockIdx.y * 128;
    const int r_st = t >> 1;        // 0..127: one row per thread-pair
    const int seg  = (t & 1) * 16;  // halves 0..15 or 16..31
    f32x4 acc[2][8] = {};
    for (int k0 = 0; k0 < K; k0 += 32) {
        int gr = row0 + r_st;
        f16x8 av0 = {0,0,0,0,0,0,0,0}, av1 = {0,0,0,0,0,0,0,0};
        if (gr < nrows) {
            av0 = *(const f16x8*)&A[(size_t)gr * K + k0 + seg];
            av1 = *(const f16x8*)&A[(size_t)gr * K + k0 + seg + 8];
        }
        *(f16x8*)&As[r_st * LDK + seg]     = av0;
        *(f16x8*)&As[r_st * LDK + seg + 8] = av1;
        f16x8 bv0 = *(const f16x8*)&Wt[(size_t)(col0 + r_st) * K + k0 + seg];
        f16x8 bv1 = *(const f16x8*)&Wt[(size_t)(col0 + r_st) * K + k0 + seg + 8];
        *(f16x8*)&Bs[r_st * LDK + seg]     = bv0;
        *(f16x8*)&Bs[r_st * LDK + seg + 8] = bv1;
        __syncthreads();
        f16x8 af0 = *(const f16x8*)&As[(w * 32 + m) * LDK + quad * 8];
        f16x8 af1 = *(const f16x8*)&As[(w * 32 + 16 + m) * LDK + quad * 8];
        #pragma unroll
        for (int g = 0; g < 8; ++g) {
            f16x8 bf = *(const f16x8*)&Bs[(g * 16 + m) * LDK + quad * 8];
            acc[0][g] = __builtin_amdgcn_mfma_f32_16x16x32_f16(af0, bf, acc[0][g], 0, 0, 0);
            acc[1][g] = __builtin_amdgcn_mfma_f32_16x16x32_f16(af1, bf, acc[1][g], 0, 0, 0);
        }
        __syncthreads();
    }
    #pragma unroll
    for (int rb = 0; rb < 2; ++rb) {
        #pragma unroll
        for (int g = 0; g < 8; ++g) {
            #pragma unroll
            for (int reg = 0; reg < 4; ++reg) {
                int gr = row0 + w * 32 + rb * 16 + quad * 4 + reg;
                int gc = col0 + g * 16 + m;
                if (gr < nrows) O[(size_t)gr * CN + gc] = (f16)acc[rb][g][reg];
            }
        }
    }
    if constexpr (H > 0) {
        constexpr int D = CN / H;
        const int head = col0 / D;   // col tile = 128 = one head
        float ps[2][4] = {}, pd[2][4] = {};
        #pragma unroll
        for (int g = 0; g < 8; ++g) {
            int col = col0 + g * 16 + m;
            float a_s = asrc[col], a_d = adst[col];
            #pragma unroll
            for (int rb = 0; rb < 2; ++rb) {
                #pragma unroll
                for (int reg = 0; reg < 4; ++reg) {
                    ps[rb][reg] += acc[rb][g][reg] * a_s;
                    pd[rb][reg] += acc[rb][g][reg] * a_d;
                }
            }
        }
        #pragma unroll
        for (int off = 1; off < 16; off <<= 1) {
            #pragma unroll
            for (int rb = 0; rb < 2; ++rb) {
                #pragma unroll
                for (int reg = 0; reg < 4; ++reg) {
                    ps[rb][reg] += __shfl_xor(ps[rb][reg], off, 64);
                    pd[rb][reg] += __shfl_xor(pd[rb][reg], off, 64);
                }
            }
        }
        if (m == 0) {
            #pragma unroll
            for (int rb = 0; rb < 2; ++rb) {
                #pragma unroll
                for (int reg = 0; reg < 4; ++reg) {
                    int gr = row0 + w * 32 + rb * 16 + quad * 4 + reg;
                    if (gr < nrows) {
                        atomicAdd(&als[gr * H + head], ps[rb][reg]);
                        atomicAdd(&ald[gr * H + head], pd[rb][reg]);
                    }
                }
            }
        }
    }
}

// ----- layer-1 per-head GEMM with fused bias+ELU -----
__global__ __launch_bounds__(256) void k_gemm1h(const f16* __restrict__ A,
                                                const f16* __restrict__ Wt1,
                                                const float* __restrict__ bias,
                                                f16* __restrict__ O,
                                                int nrows)
{
    constexpr int LDA = 40;
    __shared__ f16 As[64 * LDA];
    __shared__ f16 Bs[64 * LDA];
    const int t = threadIdx.x;
    const int w = t >> 6;
    const int lane = t & 63;
    const int m = lane & 15;
    const int quad = lane >> 4;
    const int row0 = blockIdx.x * 64;
    const int head = blockIdx.y;
    const int r_st = t >> 2;
    const int seg  = (t & 3) * 8;
    f32x4 acc[4] = {{0.f,0.f,0.f,0.f},{0.f,0.f,0.f,0.f},{0.f,0.f,0.f,0.f},{0.f,0.f,0.f,0.f}};
    for (int k0 = 0; k0 < 64; k0 += 32) {
        int gr = row0 + r_st;
        f16x8 av = {0,0,0,0,0,0,0,0};
        if (gr < nrows) av = *(const f16x8*)&A[(size_t)gr * 256 + head * 64 + k0 + seg];
        *(f16x8*)&As[r_st * LDA + seg] = av;
        f16x8 bv = *(const f16x8*)&Wt1[(size_t)head * 4096 + (size_t)r_st * 64 + k0 + seg];
        *(f16x8*)&Bs[r_st * LDA + seg] = bv;
        __syncthreads();
        f16x8 af = *(const f16x8*)&As[(w * 16 + m) * LDA + quad * 8];
        #pragma unroll
        for (int g = 0; g < 4; ++g) {
            f16x8 bf = *(const f16x8*)&Bs[(g * 16 + m) * LDA + quad * 8];
            acc[g] = __builtin_amdgcn_mfma_f32_16x16x32_f16(af, bf, acc[g], 0, 0, 0);
        }
        __syncthreads();
    }
    #pragma unroll
    for (int g = 0; g < 4; ++g) {
        #pragma unroll
        for (int reg = 0; reg < 4; ++reg) {
            int gr = row0 + w * 16 + quad * 4 + reg;
            int col = head * 64 + g * 16 + m;
            if (gr < nrows) {
                float v = acc[g][reg] + bias[col];
                v = v > 0.f ? v : (__expf(v) - 1.f);
                O[(size_t)gr * 256 + col] = (f16)v;
            }
        }
    }
}

// -------- per-edge exp weights --------
template<int H>
__global__ __launch_bounds__(256) void k_ew(const int* __restrict__ csr,
                                            const int* __restrict__ dstarr,
                                            const float* __restrict__ als,
                                            const float* __restrict__ ald,
                                            float* __restrict__ earr)
{
    int i = blockIdx.x * 256 + threadIdx.x;
    if (i >= ETOT) return;
    int s = csr[i], d = dstarr[i];
    #pragma unroll
    for (int hh = 0; hh < H; ++hh) {
        float l = als[s * H + hh] + ald[d * H + hh];
        l = l > 0.f ? l : 0.2f * l;
        earr[(size_t)i * H + hh] = __expf(fminf(l, 80.f));
    }
}

// ------- layer-1 aggregate over xc: 4 parities x 16 lanes, f16x4 loads -------
__global__ __launch_bounds__(256) void k_aggx(const int* __restrict__ rowptr,
                                              const int* __restrict__ csr,
                                              const float* __restrict__ earr, // [i][4]
                                              const f16* __restrict__ xc,
                                              f16* __restrict__ xagg)
{
    int gid = blockIdx.x * 256 + threadIdx.x;
    int n = gid >> 6, lane = gid & 63;
    if (n >= NN) return;
    int p  = lane >> 4;        // 4 edge parities
    int fl = lane & 15;        // 16 feature lanes
    int cb = fl * 4;           // 4 feats per lane
    int r0 = rowptr[n], r1 = rowptr[n + 1];
    float a0[4] = {}, a1[4] = {}, a2[4] = {}, a3[4] = {};
    float d0 = 0.f, d1 = 0.f, d2 = 0.f, d3 = 0.f;
    int i = r0;
    for (; i + 8 <= r1; i += 8) {
        int i0 = i + p, i1 = i + 4 + p;
        int s0 = csr[i0], s1 = csr[i1];
        float4 e0 = *(const float4*)&earr[(size_t)i0 * 4];
        float4 e1 = *(const float4*)&earr[(size_t)i1 * 4];
        f16x4 x0 = *(const f16x4*)&xc[(size_t)s0 * 64 + cb];
        f16x4 x1 = *(const f16x4*)&xc[(size_t)s1 * 64 + cb];
        #pragma unroll
        for (int j = 0; j < 4; ++j) {
            float v0 = (float)x0[j], v1 = (float)x1[j];
            a0[j] += e0.x * v0 + e1.x * v1;
            a1[j] += e0.y * v0 + e1.y * v1;
            a2[j] += e0.z * v0 + e1.z * v1;
            a3[j] += e0.w * v0 + e1.w * v1;
        }
        d0 += e0.x + e1.x; d1 += e0.y + e1.y;
        d2 += e0.z + e1.z; d3 += e0.w + e1.w;
    }
    for (; i < r1; i += 4) {
        int ii = i + p;
        bool v = ii < r1;
        int s0 = csr[v ? ii : r0];
        float4 e0 = *(const float4*)&earr[(size_t)(v ? ii : r0) * 4];
        if (!v) { e0.x = 0.f; e0.y = 0.f; e0.z = 0.f; e0.w = 0.f; }
        f16x4 x0 = *(const f16x4*)&xc[(size_t)s0 * 64 + cb];
        #pragma unroll
        for (int j = 0; j < 4; ++j) {
            float v0 = (float)x0[j];
            a0[j] += e0.x * v0; a1[j] += e0.y * v0;
            a2[j] += e0.z * v0; a3[j] += e0.w * v0;
        }
        d0 += e0.x; d1 += e0.y; d2 += e0.z; d3 += e0.w;
    }
    #pragma unroll
    for (int off = 16; off < 64; off <<= 1) {
        #pragma unroll
        for (int j = 0; j < 4; ++j) {
            a0[j] += __shfl_xor(a0[j], off, 64);
            a1[j] += __shfl_xor(a1[j], off, 64);
            a2[j] += __shfl_xor(a2[j], off, 64);
            a3[j] += __shfl_xor(a3[j], off, 64);
        }
        d0 += __shfl_xor(d0, off, 64);
        d1 += __shfl_xor(d1, off, 64);
        d2 += __shfl_xor(d2, off, 64);
        d3 += __shfl_xor(d3, off, 64);
    }
    if (p == 0) {
        float i0 = 1.f / d0, i1 = 1.f / d1, i2 = 1.f / d2, i3 = 1.f / d3;
        size_t base = (size_t)n * 256 + cb;
        f16x4 o0, o1, o2, o3;
        #pragma unroll
        for (int j = 0; j < 4; ++j) {
            o0[j] = (f16)(a0[j] * i0);
            o1[j] = (f16)(a1[j] * i1);
            o2[j] = (f16)(a2[j] * i2);
            o3[j] = (f16)(a3[j] * i3);
        }
        *(f16x4*)&xagg[base]       = o0;
        *(f16x4*)&xagg[base + 64]  = o1;
        *(f16x4*)&xagg[base + 128] = o2;
        *(f16x4*)&xagg[base + 192] = o3;
    }
}

// ------- layer-2 aggregate: 32 lanes/row (f16x8), 2 edge-parities, 4x unroll -------
__global__ __launch_bounds__(256) void k_agg2f(const int* __restrict__ rowptr,
                                               const int* __restrict__ csr,
                                               const float* __restrict__ earr, // [i][2]
                                               const f16* __restrict__ h,
                                               const float* __restrict__ bias,
                                               f16* __restrict__ z)
{
    int gid = blockIdx.x * 256 + threadIdx.x;
    int n = gid >> 6, lane = gid & 63;
    if (n >= NN) return;
    int p  = lane >> 5;
    int cb = (lane & 31) * 8;
    int head = cb >> 7;
    int r0 = rowptr[n], r1 = rowptr[n + 1];
    float a[8] = {};
    float den = 0.f;
    int i = r0;
    for (; i + 8 <= r1; i += 8) {
        int i0 = i + p, i1 = i + 2 + p, i2 = i + 4 + p, i3 = i + 6 + p;
        int s0 = csr[i0], s1 = csr[i1], s2 = csr[i2], s3 = csr[i3];
        float e0 = earr[(size_t)i0 * 2 + head];
        float e1 = earr[(size_t)i1 * 2 + head];
        float e2 = earr[(size_t)i2 * 2 + head];
        float e3 = earr[(size_t)i3 * 2 + head];
        f16x8 h0 = *(const f16x8*)&h[(size_t)s0 * 256 + cb];
        f16x8 h1 = *(const f16x8*)&h[(size_t)s1 * 256 + cb];
        f16x8 h2 = *(const f16x8*)&h[(size_t)s2 * 256 + cb];
        f16x8 h3 = *(const f16x8*)&h[(size_t)s3 * 256 + cb];
        #pragma unroll
        for (int j = 0; j < 8; ++j)
            a[j] += e0 * (float)h0[j] + e1 * (float)h1[j]
                  + e2 * (float)h2[j] + e3 * (float)h3[j];
        den += e0 + e1 + e2 + e3;
    }
    for (; i < r1; i += 2) {
        int ii = i + p;
        bool v = ii < r1;
        int s0 = csr[v ? ii : r0];
        float e0 = v ? earr[(size_t)ii * 2 + head] : 0.f;
        f16x8 h0 = *(const f16x8*)&h[(size_t)s0 * 256 + cb];
        #pragma unroll
        for (int j = 0; j < 8; ++j) a[j] += e0 * (float)h0[j];
        den += e0;
    }
    #pragma unroll
    for (int j = 0; j < 8; ++j) a[j] += __shfl_xor(a[j], 32, 64);
    den += __shfl_xor(den, 32, 64);
    if (p == 0) {
        float inv = 1.f / den;
        f16x8 o;
        #pragma unroll
        for (int j = 0; j < 8; ++j) {
            float v = a[j] * inv + bias[cb + j];
            v = v > 0.f ? v : (__expf(v) - 1.f);
            o[j] = (f16)v;
        }
        *(f16x8*)&z[(size_t)n * 256 + cb] = o;
    }
}

// ------- layer-3 aggregate: 16 lanes/row (f16x8), 4 edge-parities, 2x unroll -------
__global__ __launch_bounds__(256) void k_agg3(const int* __restrict__ rowptr,
                                              const int* __restrict__ csr,
                                              const float* __restrict__ earr, // [i]
                                              const f16* __restrict__ h,
                                              const float* __restrict__ bias,
                                              f16* __restrict__ z)
{
    int gid = blockIdx.x * 256 + threadIdx.x;
    int n = gid >> 6, lane = gid & 63;
    if (n >= NN) return;
    int p  = lane >> 4;
    int cb = (lane & 15) * 8;
    int r0 = rowptr[n], r1 = rowptr[n + 1];
    float a[8] = {};
    float den = 0.f;
    int i = r0;
    for (; i + 8 <= r1; i += 8) {
        int i0 = i + p, i1 = i + 4 + p;
        int s0 = csr[i0], s1 = csr[i1];
        float e0 = earr[i0], e1 = earr[i1];
        f16x8 h0 = *(const f16x8*)&h[(size_t)s0 * 128 + cb];
        f16x8 h1 = *(const f16x8*)&h[(size_t)s1 * 128 + cb];
        #pragma unroll
        for (int j = 0; j < 8; ++j)
            a[j] += e0 * (float)h0[j] + e1 * (float)h1[j];
        den += e0 + e1;
    }
    for (; i < r1; i += 4) {
        int ii = i + p;
        bool v = ii < r1;
        int s0 = csr[v ? ii : r0];
        float e0 = v ? earr[ii] : 0.f;
        f16x8 h0 = *(const f16x8*)&h[(size_t)s0 * 128 + cb];
        #pragma unroll
        for (int j = 0; j < 8; ++j) a[j] += e0 * (float)h0[j];
        den += e0;
    }
    #pragma unroll
    for (int j = 0; j < 8; ++j) {
        a[j] += __shfl_xor(a[j], 16, 64);
        a[j] += __shfl_xor(a[j], 32, 64);
    }
    den += __shfl_xor(den, 16, 64);
    den += __shfl_xor(den, 32, 64);
    if (lane < 16) {
        float inv = 1.f / den;
        f16x8 o;
        #pragma unroll
        for (int j = 0; j < 8; ++j)
            o[j] = (f16)(a[j] * inv + bias[cb + j]);
        *(f16x8*)&z[(size_t)n * 128 + cb] = o;
    }
}

// ---------- MFMA decoder: 64 edges/block, ef[64][256]f16 @ Wtl[64][256]^T ----------
#define DLDA 264
__global__ __launch_bounds__(256) void k_decm(const f16* __restrict__ z3,
                                              const int* __restrict__ eli,
                                              const int* __restrict__ ntypes,
                                              const f16* __restrict__ Wtl,  // [64][256]
                                              const float* __restrict__ bl1,
                                              const float* __restrict__ Wl2,
                                              const float* __restrict__ bl2,
                                              const float* __restrict__ tb,
                                              float* __restrict__ out)
{
    __shared__ f16 As[64 * DLDA];
    __shared__ int sls[64], sld[64];
    const int t = threadIdx.x;
    const int e0 = blockIdx.x * 64;
    if (t < 64) {
        int e = e0 + t;
        sls[t] = (e < ELN) ? eli[e] : 0;
        sld[t] = (e < ELN) ? eli[ELN + e] : 0;
    }
    __syncthreads();
    {
        int r = t & 63;
        int seg = t >> 6;
        int base = seg * 64;
        int node = (base < 128) ? sls[r] : sld[r];
        int zoff = base & 127;
        #pragma unroll
        for (int j = 0; j < 8; ++j) {
            f16x8 v = *(const f16x8*)&z3[(size_t)node * 128 + zoff + j * 8];
            *(f16x8*)&As[r * DLDA + base + j * 8] = v;
        }
    }
    __syncthreads();
    const int w = t >> 6;
    const int lane = t & 63;
    const int m = lane & 15;
    const int quad = lane >> 4;
    f32x4 acc[4] = {{0.f,0.f,0.f,0.f},{0.f,0.f,0.f,0.f},{0.f,0.f,0.f,0.f},{0.f,0.f,0.f,0.f}};
    for (int k0 = 0; k0 < 256; k0 += 32) {
        f16x8 af = *(const f16x8*)&As[(w * 16 + m) * DLDA + k0 + quad * 8];
        #pragma unroll
        for (int g = 0; g < 4; ++g) {
            f16x8 bf = *(const f16x8*)&Wtl[(size_t)(g * 16 + m) * 256 + k0 + quad * 8];
            acc[g] = __builtin_amdgcn_mfma_f32_16x16x32_f16(af, bf, acc[g], 0, 0, 0);
        }
    }
    float s[4] = {0.f, 0.f, 0.f, 0.f};
    #pragma unroll
    for (int g = 0; g < 4; ++g) {
        int col = g * 16 + m;
        float b = bl1[col], wv = Wl2[col];
        #pragma unroll
        for (int reg = 0; reg < 4; ++reg) {
            float hv = fmaxf(acc[g][reg] + b, 0.f);
            s[reg] += hv * wv;
        }
    }
    #pragma unroll
    for (int off = 1; off < 16; off <<= 1) {
        #pragma unroll
        for (int reg = 0; reg < 4; ++reg) s[reg] += __shfl_xor(s[reg], off, 64);
    }
    if (m == 0) {
        float b2v = bl2[0];
        #pragma unroll
        for (int reg = 0; reg < 4; ++reg) {
            int r = w * 16 + quad * 4 + reg;
            int e = e0 + r;
            if (e < ELN) {
                out[e] = s[reg] + b2v +
                         tb[(size_t)ntypes[sls[r]] * NT + ntypes[sld[r]]];
            }
        }
    }
}

// ---------------- launch ----------------
extern "C" void kernel_launch(void* const* d_in, const int* in_sizes, int n_in,
                              void* d_out, int out_size, void* d_ws, size_t ws_size,
                              hipStream_t stream)
{
    const float* x   = (const float*)d_in[0];
    const int*   ei  = (const int*)d_in[1];
    const int*   eli = (const int*)d_in[2];
    const float* emb = (const float*)d_in[3];
    const float* W1  = (const float*)d_in[4];
    const float* as1 = (const float*)d_in[5];
    const float* ad1 = (const float*)d_in[6];
    const float* b1  = (const float*)d_in[7];
    const float* W2  = (const float*)d_in[8];
    const float* as2 = (const float*)d_in[9];
    const float* ad2 = (const float*)d_in[10];
    const float* b2  = (const float*)d_in[11];
    const float* W3  = (const float*)d_in[12];
    const float* as3 = (const float*)d_in[13];
    const float* ad3 = (const float*)d_in[14];
    const float* b3  = (const float*)d_in[15];
    const float* Wl1 = (const float*)d_in[16];
    const float* bl1 = (const float*)d_in[17];
    const float* Wl2 = (const float*)d_in[18];
    const float* bl2 = (const float*)d_in[19];
    const float* tb  = (const float*)d_in[20];
    float* out = (float*)d_out;

    char* ws = (char*)d_ws;
    size_t off = 0;
    auto alloc = [&](size_t bytes) { size_t o = off; off = (off + bytes + 255) & ~(size_t)255; return o; };
    int*   ntypes = (int*)  (ws + alloc((size_t)NN * 4));
    f16*   xc16   = (f16*)  (ws + alloc((size_t)NN * 64 * 2));
    int*   rowptr = (int*)  (ws + alloc((size_t)(NN + 1) * 4));
    int*   csr    = (int*)  (ws + alloc((size_t)ETOT * 4));
    int*   dstarr = (int*)  (ws + alloc((size_t)ETOT * 4));
    int*   bcur   = (int*)  (ws + alloc((size_t)(NBUCK + 1) * 4));
    int*   boff   = (int*)  (ws + alloc((size_t)(NBUCK + 1) * 4));
    // score buffers: [als1:4NN][ald1:4NN][als2:2NN][ald2:2NN][als3:NN][ald3:NN]
    float* scores = (float*)(ws + alloc((size_t)NN * 14 * 4));
    float* als1 = scores;
    float* ald1 = scores + (size_t)NN * 4;
    float* als2 = scores + (size_t)NN * 8;
    float* ald2 = scores + (size_t)NN * 10;
    float* als3 = scores + (size_t)NN * 12;
    float* ald3 = scores + (size_t)NN * 13;
    float* earr   = (float*)(ws + alloc((size_t)ETOT * 4 * 4));
    f16*   h16    = (f16*)  (ws + alloc((size_t)NN * 256 * 2));   // also xagg
    f16*   z16    = (f16*)  (ws + alloc((size_t)NN * 256 * 2));
    f16*   Wt1    = (f16*)  (ws + alloc((size_t)4 * 64 * 64 * 2));
    f16*   Wt2    = (f16*)  (ws + alloc((size_t)256 * 256 * 2));
    f16*   Wt3    = (f16*)  (ws + alloc((size_t)128 * 256 * 2));
    f16*   Wtl    = (f16*)  (ws + alloc((size_t)64 * 256 * 2));
    float* a1ps   = (float*)(ws + alloc(256 * 4));
    float* a1pd   = (float*)(ws + alloc(256 * 4));

    // bucket pair buffer (9.6 MB) aliases earr (13.6 MB): earr is first
    // written by k_ew<4>, strictly after the CSR build on this stream.
    int2* bbuf = (int2*)earr;

    hipMemsetAsync(bcur, 0, (size_t)(NBUCK + 1) * 4, stream);
    hipMemsetAsync(als2, 0, (size_t)NN * 6 * 4, stream);   // als2,ald2,als3,ald3

    const int gE   = (ETOT + 255) / 256;
    const int RB   = (NN + 63) / 64;       // 782
    const int RB2  = (NN + 127) / 128;     // 391
    const int gW1  = (NN + 3) / 4;         // 1 wave/node

    k_pre1<<<1, 256, 0, stream>>>(W1, as1, ad1, a1ps, a1pd);
    k_prepatt<<<gW1, 256, 0, stream>>>(x, emb, a1ps, a1pd, xc16, ntypes, als1, ald1);
    k_cvtall<<<(131072 + 255) / 256, 256, 0, stream>>>(W1, W2, W3, Wl1, Wt1, Wt2, Wt3, Wtl);

    // CSR build: bucket scatter -> bucket scan -> per-bucket counting sort
    k_bucket<<<(ETOT + CHUNK - 1) / CHUNK, 256, 0, stream>>>(ei, bcur, bbuf);
    k_bscan <<<1, 512, 0, stream>>>(bcur, boff);
    k_csrb  <<<NBUCK, 256, 0, stream>>>(bcur, boff, bbuf, rowptr, csr, dstarr);

    // Layer 1 (linearity-swapped; scores from k_prepatt)
    k_ew<4><<<gE, 256, 0, stream>>>(csr, dstarr, als1, ald1, earr);
    k_aggx<<<gW1, 256, 0, stream>>>(rowptr, csr, earr, xc16, h16 /*xagg*/);
    k_gemm1h<<<dim3(RB, 4), 256, 0, stream>>>(h16 /*xagg*/, Wt1, b1, z16, NN);

    // Layer 2 (att fused into 128x128 GEMM epilogue; buffers pre-zeroed upfront)
    k_gemmw<256, 256, 2><<<dim3(RB2, 2), 256, 0, stream>>>(z16, Wt2, h16, NN, as2, ad2, als2, ald2);
    k_ew<2><<<gE, 256, 0, stream>>>(csr, dstarr, als2, ald2, earr);
    k_agg2f<<<gW1, 256, 0, stream>>>(rowptr, csr, earr, h16, b2, z16);

    // Layer 3 (att fused into 128x128 GEMM epilogue; buffers pre-zeroed upfront)
    k_gemmw<256, 128, 1><<<dim3(RB2, 1), 256, 0, stream>>>(z16, Wt3, h16, NN, as3, ad3, als3, ald3);
    k_ew<1><<<gE, 256, 0, stream>>>(csr, dstarr, als3, ald3, earr);
    k_agg3<<<gW1, 256, 0, stream>>>(rowptr, csr, earr, h16, b3, z16);

    // Decoder (MFMA)
    k_decm<<<(ELN + 63) / 64, 256, 0, stream>>>(z16, eli, ntypes, Wtl, bl1, Wl2, bl2, tb, out);
}

// Round 6
// 397.241 us; speedup vs baseline: 2.1043x; 1.0348x over previous
//
#include <hip/hip_runtime.h>
#include <hip/hip_bf16.h>

#define NN 50000
#define EE 800000
#define ELN 100000
#define ETOT (EE + NN)
#define NT 311

// ---- bucketed CSR build params ----
#define NBUCK ((NN + 127) >> 7)     // 391 buckets of 128 nodes
#define BCAP 3072                   // capacity per bucket (mean 2174, ~19 sigma margin)
#define CHUNK 8192                  // edges per k_bucket block

typedef _Float16 f16;
typedef f16 f16x8 __attribute__((ext_vector_type(8)));
typedef f16 f16x4 __attribute__((ext_vector_type(4)));
typedef f16 f16x2 __attribute__((ext_vector_type(2)));
typedef float f32x4 __attribute__((ext_vector_type(4)));

__device__ __forceinline__ float edge_alpha(float l)
{
    l = l > 0.f ? l : 0.2f * l;
    return __expf(fminf(l, 80.f));
}

// ------- fused prep + layer-1 att scores: one wave per node -------
__global__ __launch_bounds__(256) void k_prepatt(const float* __restrict__ x,
                                                 const float* __restrict__ emb,
                                                 const float* __restrict__ a1ps,
                                                 const float* __restrict__ a1pd,
                                                 f16* __restrict__ xc,
                                                 int* __restrict__ ntypes,
                                                 float* __restrict__ als,
                                                 float* __restrict__ ald)
{
    int gid = blockIdx.x * 256 + threadIdx.x;
    int n = gid >> 6, lane = gid & 63;
    if (n >= NN) return;
    int tpe = (int)x[(size_t)n * 33];
    tpe = tpe < 0 ? 0 : (tpe > NT - 1 ? NT - 1 : tpe);
    if (lane == 0) ntypes[n] = tpe;
    float v;
    if (lane < 16)      v = emb[tpe * 16 + lane];
    else if (lane < 48) v = x[(size_t)n * 33 + 1 + (lane - 16)];
    else                v = 0.f;
    f16 hv = (f16)v;
    xc[(size_t)n * 64 + lane] = hv;
    float xv = (float)hv;
    float ps[4], pd[4];
    #pragma unroll
    for (int h = 0; h < 4; ++h) {
        ps[h] = xv * a1ps[h * 64 + lane];
        pd[h] = xv * a1pd[h * 64 + lane];
    }
    #pragma unroll
    for (int off = 32; off > 0; off >>= 1) {
        #pragma unroll
        for (int h = 0; h < 4; ++h) {
            ps[h] += __shfl_xor(ps[h], off, 64);
            pd[h] += __shfl_xor(pd[h], off, 64);
        }
    }
    if (lane == 0) {
        #pragma unroll
        for (int h = 0; h < 4; ++h) {
            als[n * 4 + h] = ps[h];
            ald[n * 4 + h] = pd[h];
        }
    }
}

// ---- all weight conversions in one kernel ----
__global__ __launch_bounds__(256) void k_cvtall(const float* __restrict__ W1,
                                                const float* __restrict__ W2,
                                                const float* __restrict__ W3,
                                                const float* __restrict__ Wl1,
                                                f16* __restrict__ Wt1,
                                                f16* __restrict__ Wt2,
                                                f16* __restrict__ Wt3,
                                                f16* __restrict__ Wtl)
{
    int idx = blockIdx.x * 256 + threadIdx.x;
    if (idx < 16384) {
        int h = idx >> 12, c = (idx >> 6) & 63, k = idx & 63;
        Wt1[idx] = (k < 48) ? (f16)W1[(size_t)k * 256 + h * 64 + c] : (f16)0.f;
    } else if (idx < 81920) {
        int i = idx - 16384;
        int c = i >> 8, k = i & 255;
        Wt2[i] = (f16)W2[(size_t)k * 256 + c];
    } else if (idx < 114688) {
        int i = idx - 81920;
        int c = i >> 8, k = i & 255;
        Wt3[i] = (f16)W3[(size_t)k * 128 + c];
    } else if (idx < 131072) {
        int i = idx - 114688;
        int c = i >> 8, k = i & 255;
        Wtl[i] = (f16)Wl1[(size_t)k * 64 + c];
    }
}

// ---- fold a_src/a_dst through W1 ----
__global__ __launch_bounds__(256) void k_pre1(const float* __restrict__ W1,
                                              const float* __restrict__ as1,
                                              const float* __restrict__ ad1,
                                              float* __restrict__ a1ps,
                                              float* __restrict__ a1pd)
{
    int t = threadIdx.x;
    int h = t >> 6, k = t & 63;
    float ss = 0.f, sd = 0.f;
    if (k < 48) {
        for (int d = 0; d < 64; ++d) {
            float w = W1[(size_t)k * 256 + h * 64 + d];
            ss += w * as1[h * 64 + d];
            sd += w * ad1[h * 64 + d];
        }
    }
    a1ps[t] = ss;
    a1pd[t] = sd;
}

// ---------------- bucketed CSR build ----------------
__global__ __launch_bounds__(256) void k_bucket(const int* __restrict__ ei,
                                                int* __restrict__ bcur,
                                                int2* __restrict__ bbuf)
{
    __shared__ int hist[NBUCK];
    __shared__ int gbase[NBUCK];
    const int t = threadIdx.x;
    for (int i = t; i < NBUCK; i += 256) hist[i] = 0;
    __syncthreads();
    const int e0 = blockIdx.x * CHUNK;
    const int eend = min(e0 + CHUNK, ETOT);
    for (int e = e0 + t; e < eend; e += 256) {
        int dst = (e < EE) ? ei[EE + e] : (e - EE);
        atomicAdd(&hist[dst >> 7], 1);
    }
    __syncthreads();
    for (int i = t; i < NBUCK; i += 256) {
        int c = hist[i];
        gbase[i] = c ? atomicAdd(&bcur[i], c) : 0;
        hist[i] = 0;     // reuse as local cursor
    }
    __syncthreads();
    for (int e = e0 + t; e < eend; e += 256) {
        int src, dst;
        if (e < EE) { src = ei[e]; dst = ei[EE + e]; }
        else        { src = e - EE; dst = src; }
        int b = dst >> 7;
        int pos = gbase[b] + atomicAdd(&hist[b], 1);
        if (pos < BCAP)
            bbuf[(size_t)b * BCAP + pos] = make_int2(src, dst);
    }
}

__global__ __launch_bounds__(512) void k_bscan(const int* __restrict__ bcur,
                                               int* __restrict__ boff)
{
    __shared__ int s[512];
    int t = threadIdx.x;
    int v = (t < NBUCK) ? min(bcur[t], BCAP) : 0;
    s[t] = v;
    __syncthreads();
    #pragma unroll
    for (int off = 1; off < 512; off <<= 1) {
        int u = (t >= off) ? s[t - off] : 0;
        __syncthreads();
        s[t] += u;
        __syncthreads();
    }
    if (t < NBUCK) boff[t] = s[t] - v;
    if (t == NBUCK - 1) boff[NBUCK] = s[t];
}

// Pass B: one block per bucket. LDS counting sort by exact dst, emit rowptr
// directly, write csr fully coalesced. (dst array not materialized — agg
// kernels know dst == owning node.)
__global__ __launch_bounds__(256) void k_csrb(const int* __restrict__ bcur,
                                              const int* __restrict__ boff,
                                              const int2* __restrict__ bbuf,
                                              int* __restrict__ rowptr,
                                              int* __restrict__ csr)
{
    __shared__ int nh[128];     // per-node hist -> inclusive prefix
    __shared__ int loff[128];   // per-node exclusive local offset
    __shared__ int ncur[128];
    __shared__ int ssrc[BCAP];
    const int b = blockIdx.x;
    const int t = threadIdx.x;
    const int n0 = b << 7;
    const int cnt = min(bcur[b], BCAP);
    const int base = boff[b];
    const size_t bb = (size_t)b * BCAP;
    if (t < 128) { nh[t] = 0; ncur[t] = 0; }
    __syncthreads();
    for (int i = t; i < cnt; i += 256)
        atomicAdd(&nh[bbuf[bb + i].y - n0], 1);
    __syncthreads();
    int myc = (t < 128) ? nh[t] : 0;
    #pragma unroll
    for (int off = 1; off < 128; off <<= 1) {
        int u = (t >= off && t < 128) ? nh[t - off] : 0;
        __syncthreads();
        if (t < 128) nh[t] += u;
        __syncthreads();
    }
    if (t < 128) {
        int ex = nh[t] - myc;
        loff[t] = ex;
        int n = n0 + t;
        if (n < NN) rowptr[n] = base + ex;
    }
    __syncthreads();
    for (int i = t; i < cnt; i += 256) {
        int2 p = bbuf[bb + i];
        int ln = p.y - n0;
        int pos = loff[ln] + atomicAdd(&ncur[ln], 1);
        ssrc[pos] = p.x;
    }
    __syncthreads();
    for (int i = t; i < cnt; i += 256)
        csr[base + i] = ssrc[i];
    if (b == 0 && t == 0) rowptr[NN] = boff[NBUCK];
}

// ------- MFMA f16 GEMM, 128x128 tile, optional fused attention-score partials -------
template<int K, int CN, int H>
__global__ __launch_bounds__(256) void k_gemmw(const f16* __restrict__ A,
                                               const f16* __restrict__ Wt,
                                               f16* __restrict__ O,
                                               int nrows,
                                               const float* __restrict__ asrc,
                                               const float* __restrict__ adst,
                                               float* __restrict__ als,
                                               float* __restrict__ ald)
{
    constexpr int LDK = 40;
    __shared__ f16 As[128 * LDK];
    __shared__ f16 Bs[128 * LDK];
    const int t = threadIdx.x;
    const int w = t >> 6;
    const int lane = t & 63;
    const int m = lane & 15;
    const int quad = lane >> 4;
    const int row0 = blockIdx.x * 128;
    const int col0 = blockIdx.y * 128;
    const int r_st = t >> 1;        // 0..127: one row per thread-pair
    const int seg  = (t & 1) * 16;  // halves 0..15 or 16..31
    f32x4 acc[2][8] = {};
    for (int k0 = 0; k0 < K; k0 += 32) {
        int gr = row0 + r_st;
        f16x8 av0 = {0,0,0,0,0,0,0,0}, av1 = {0,0,0,0,0,0,0,0};
        if (gr < nrows) {
            av0 = *(const f16x8*)&A[(size_t)gr * K + k0 + seg];
            av1 = *(const f16x8*)&A[(size_t)gr * K + k0 + seg + 8];
        }
        *(f16x8*)&As[r_st * LDK + seg]     = av0;
        *(f16x8*)&As[r_st * LDK + seg + 8] = av1;
        f16x8 bv0 = *(const f16x8*)&Wt[(size_t)(col0 + r_st) * K + k0 + seg];
        f16x8 bv1 = *(const f16x8*)&Wt[(size_t)(col0 + r_st) * K + k0 + seg + 8];
        *(f16x8*)&Bs[r_st * LDK + seg]     = bv0;
        *(f16x8*)&Bs[r_st * LDK + seg + 8] = bv1;
        __syncthreads();
        f16x8 af0 = *(const f16x8*)&As[(w * 32 + m) * LDK + quad * 8];
        f16x8 af1 = *(const f16x8*)&As[(w * 32 + 16 + m) * LDK + quad * 8];
        #pragma unroll
        for (int g = 0; g < 8; ++g) {
            f16x8 bf = *(const f16x8*)&Bs[(g * 16 + m) * LDK + quad * 8];
            acc[0][g] = __builtin_amdgcn_mfma_f32_16x16x32_f16(af0, bf, acc[0][g], 0, 0, 0);
            acc[1][g] = __builtin_amdgcn_mfma_f32_16x16x32_f16(af1, bf, acc[1][g], 0, 0, 0);
        }
        __syncthreads();
    }
    #pragma unroll
    for (int rb = 0; rb < 2; ++rb) {
        #pragma unroll
        for (int g = 0; g < 8; ++g) {
            #pragma unroll
            for (int reg = 0; reg < 4; ++reg) {
                int gr = row0 + w * 32 + rb * 16 + quad * 4 + reg;
                int gc = col0 + g * 16 + m;
                if (gr < nrows) O[(size_t)gr * CN + gc] = (f16)acc[rb][g][reg];
            }
        }
    }
    if constexpr (H > 0) {
        constexpr int D = CN / H;
        const int head = col0 / D;   // col tile = 128 = one head
        float ps[2][4] = {}, pd[2][4] = {};
        #pragma unroll
        for (int g = 0; g < 8; ++g) {
            int col = col0 + g * 16 + m;
            float a_s = asrc[col], a_d = adst[col];
            #pragma unroll
            for (int rb = 0; rb < 2; ++rb) {
                #pragma unroll
                for (int reg = 0; reg < 4; ++reg) {
                    ps[rb][reg] += acc[rb][g][reg] * a_s;
                    pd[rb][reg] += acc[rb][g][reg] * a_d;
                }
            }
        }
        #pragma unroll
        for (int off = 1; off < 16; off <<= 1) {
            #pragma unroll
            for (int rb = 0; rb < 2; ++rb) {
                #pragma unroll
                for (int reg = 0; reg < 4; ++reg) {
                    ps[rb][reg] += __shfl_xor(ps[rb][reg], off, 64);
                    pd[rb][reg] += __shfl_xor(pd[rb][reg], off, 64);
                }
            }
        }
        if (m == 0) {
            #pragma unroll
            for (int rb = 0; rb < 2; ++rb) {
                #pragma unroll
                for (int reg = 0; reg < 4; ++reg) {
                    int gr = row0 + w * 32 + rb * 16 + quad * 4 + reg;
                    if (gr < nrows) {
                        atomicAdd(&als[gr * H + head], ps[rb][reg]);
                        atomicAdd(&ald[gr * H + head], pd[rb][reg]);
                    }
                }
            }
        }
    }
}

// ----- layer-1 per-head GEMM with fused bias+ELU -----
__global__ __launch_bounds__(256) void k_gemm1h(const f16* __restrict__ A,
                                                const f16* __restrict__ Wt1,
                                                const float* __restrict__ bias,
                                                f16* __restrict__ O,
                                                int nrows)
{
    constexpr int LDA = 40;
    __shared__ f16 As[64 * LDA];
    __shared__ f16 Bs[64 * LDA];
    const int t = threadIdx.x;
    const int w = t >> 6;
    const int lane = t & 63;
    const int m = lane & 15;
    const int quad = lane >> 4;
    const int row0 = blockIdx.x * 64;
    const int head = blockIdx.y;
    const int r_st = t >> 2;
    const int seg  = (t & 3) * 8;
    f32x4 acc[4] = {{0.f,0.f,0.f,0.f},{0.f,0.f,0.f,0.f},{0.f,0.f,0.f,0.f},{0.f,0.f,0.f,0.f}};
    for (int k0 = 0; k0 < 64; k0 += 32) {
        int gr = row0 + r_st;
        f16x8 av = {0,0,0,0,0,0,0,0};
        if (gr < nrows) av = *(const f16x8*)&A[(size_t)gr * 256 + head * 64 + k0 + seg];
        *(f16x8*)&As[r_st * LDA + seg] = av;
        f16x8 bv = *(const f16x8*)&Wt1[(size_t)head * 4096 + (size_t)r_st * 64 + k0 + seg];
        *(f16x8*)&Bs[r_st * LDA + seg] = bv;
        __syncthreads();
        f16x8 af = *(const f16x8*)&As[(w * 16 + m) * LDA + quad * 8];
        #pragma unroll
        for (int g = 0; g < 4; ++g) {
            f16x8 bf = *(const f16x8*)&Bs[(g * 16 + m) * LDA + quad * 8];
            acc[g] = __builtin_amdgcn_mfma_f32_16x16x32_f16(af, bf, acc[g], 0, 0, 0);
        }
        __syncthreads();
    }
    #pragma unroll
    for (int g = 0; g < 4; ++g) {
        #pragma unroll
        for (int reg = 0; reg < 4; ++reg) {
            int gr = row0 + w * 16 + quad * 4 + reg;
            int col = head * 64 + g * 16 + m;
            if (gr < nrows) {
                float v = acc[g][reg] + bias[col];
                v = v > 0.f ? v : (__expf(v) - 1.f);
                O[(size_t)gr * 256 + col] = (f16)v;
            }
        }
    }
}

// ------- layer-1 aggregate over xc, fused alpha: 4 parities x 16 lanes, f16x4 -------
__global__ __launch_bounds__(256) void k_aggx(const int* __restrict__ rowptr,
                                              const int* __restrict__ csr,
                                              const float* __restrict__ als,  // [n][4]
                                              const float* __restrict__ ald,  // [n][4]
                                              const f16* __restrict__ xc,
                                              f16* __restrict__ xagg)
{
    int gid = blockIdx.x * 256 + threadIdx.x;
    int n = gid >> 6, lane = gid & 63;
    if (n >= NN) return;
    int p  = lane >> 4;        // 4 edge parities
    int fl = lane & 15;        // 16 feature lanes
    int cb = fl * 4;           // 4 feats per lane
    int r0 = rowptr[n], r1 = rowptr[n + 1];
    float4 dl = *(const float4*)&ald[(size_t)n * 4];
    float a0[4] = {}, a1[4] = {}, a2[4] = {}, a3[4] = {};
    float d0 = 0.f, d1 = 0.f, d2 = 0.f, d3 = 0.f;
    int i = r0;
    for (; i + 8 <= r1; i += 8) {
        int i0 = i + p, i1 = i + 4 + p;
        int s0 = csr[i0], s1 = csr[i1];
        f16x4 x0 = *(const f16x4*)&xc[(size_t)s0 * 64 + cb];
        f16x4 x1 = *(const f16x4*)&xc[(size_t)s1 * 64 + cb];
        float4 A0 = *(const float4*)&als[(size_t)s0 * 4];
        float4 A1 = *(const float4*)&als[(size_t)s1 * 4];
        float4 e0, e1;
        e0.x = edge_alpha(A0.x + dl.x); e1.x = edge_alpha(A1.x + dl.x);
        e0.y = edge_alpha(A0.y + dl.y); e1.y = edge_alpha(A1.y + dl.y);
        e0.z = edge_alpha(A0.z + dl.z); e1.z = edge_alpha(A1.z + dl.z);
        e0.w = edge_alpha(A0.w + dl.w); e1.w = edge_alpha(A1.w + dl.w);
        #pragma unroll
        for (int j = 0; j < 4; ++j) {
            float v0 = (float)x0[j], v1 = (float)x1[j];
            a0[j] += e0.x * v0 + e1.x * v1;
            a1[j] += e0.y * v0 + e1.y * v1;
            a2[j] += e0.z * v0 + e1.z * v1;
            a3[j] += e0.w * v0 + e1.w * v1;
        }
        d0 += e0.x + e1.x; d1 += e0.y + e1.y;
        d2 += e0.z + e1.z; d3 += e0.w + e1.w;
    }
    for (; i < r1; i += 4) {
        int ii = i + p;
        bool v = ii < r1;
        int s0 = csr[v ? ii : r0];
        f16x4 x0 = *(const f16x4*)&xc[(size_t)s0 * 64 + cb];
        float4 A0 = *(const float4*)&als[(size_t)s0 * 4];
        float4 e0;
        e0.x = v ? edge_alpha(A0.x + dl.x) : 0.f;
        e0.y = v ? edge_alpha(A0.y + dl.y) : 0.f;
        e0.z = v ? edge_alpha(A0.z + dl.z) : 0.f;
        e0.w = v ? edge_alpha(A0.w + dl.w) : 0.f;
        #pragma unroll
        for (int j = 0; j < 4; ++j) {
            float v0 = (float)x0[j];
            a0[j] += e0.x * v0; a1[j] += e0.y * v0;
            a2[j] += e0.z * v0; a3[j] += e0.w * v0;
        }
        d0 += e0.x; d1 += e0.y; d2 += e0.z; d3 += e0.w;
    }
    #pragma unroll
    for (int off = 16; off < 64; off <<= 1) {
        #pragma unroll
        for (int j = 0; j < 4; ++j) {
            a0[j] += __shfl_xor(a0[j], off, 64);
            a1[j] += __shfl_xor(a1[j], off, 64);
            a2[j] += __shfl_xor(a2[j], off, 64);
            a3[j] += __shfl_xor(a3[j], off, 64);
        }
        d0 += __shfl_xor(d0, off, 64);
        d1 += __shfl_xor(d1, off, 64);
        d2 += __shfl_xor(d2, off, 64);
        d3 += __shfl_xor(d3, off, 64);
    }
    if (p == 0) {
        float i0 = 1.f / d0, i1 = 1.f / d1, i2 = 1.f / d2, i3 = 1.f / d3;
        size_t base = (size_t)n * 256 + cb;
        f16x4 o0, o1, o2, o3;
        #pragma unroll
        for (int j = 0; j < 4; ++j) {
            o0[j] = (f16)(a0[j] * i0);
            o1[j] = (f16)(a1[j] * i1);
            o2[j] = (f16)(a2[j] * i2);
            o3[j] = (f16)(a3[j] * i3);
        }
        *(f16x4*)&xagg[base]       = o0;
        *(f16x4*)&xagg[base + 64]  = o1;
        *(f16x4*)&xagg[base + 128] = o2;
        *(f16x4*)&xagg[base + 192] = o3;
    }
}

// ------- layer-2 aggregate, fused alpha: 32 lanes/row (f16x8), 2 parities, 4x -------
__global__ __launch_bounds__(256) void k_agg2f(const int* __restrict__ rowptr,
                                               const int* __restrict__ csr,
                                               const float* __restrict__ als,  // [n][2]
                                               const float* __restrict__ ald,  // [n][2]
                                               const f16* __restrict__ h,
                                               const float* __restrict__ bias,
                                               f16* __restrict__ z)
{
    int gid = blockIdx.x * 256 + threadIdx.x;
    int n = gid >> 6, lane = gid & 63;
    if (n >= NN) return;
    int p  = lane >> 5;
    int cb = (lane & 31) * 8;
    int head = cb >> 7;
    int r0 = rowptr[n], r1 = rowptr[n + 1];
    float dd = ald[(size_t)n * 2 + head];
    float a[8] = {};
    float den = 0.f;
    int i = r0;
    for (; i + 8 <= r1; i += 8) {
        int i0 = i + p, i1 = i + 2 + p, i2 = i + 4 + p, i3 = i + 6 + p;
        int s0 = csr[i0], s1 = csr[i1], s2 = csr[i2], s3 = csr[i3];
        f16x8 h0 = *(const f16x8*)&h[(size_t)s0 * 256 + cb];
        f16x8 h1 = *(const f16x8*)&h[(size_t)s1 * 256 + cb];
        f16x8 h2 = *(const f16x8*)&h[(size_t)s2 * 256 + cb];
        f16x8 h3 = *(const f16x8*)&h[(size_t)s3 * 256 + cb];
        float w0 = als[(size_t)s0 * 2 + head];
        float w1 = als[(size_t)s1 * 2 + head];
        float w2 = als[(size_t)s2 * 2 + head];
        float w3 = als[(size_t)s3 * 2 + head];
        float e0 = edge_alpha(w0 + dd);
        float e1 = edge_alpha(w1 + dd);
        float e2 = edge_alpha(w2 + dd);
        float e3 = edge_alpha(w3 + dd);
        #pragma unroll
        for (int j = 0; j < 8; ++j)
            a[j] += e0 * (float)h0[j] + e1 * (float)h1[j]
                  + e2 * (float)h2[j] + e3 * (float)h3[j];
        den += e0 + e1 + e2 + e3;
    }
    for (; i < r1; i += 2) {
        int ii = i + p;
        bool v = ii < r1;
        int s0 = csr[v ? ii : r0];
        f16x8 h0 = *(const f16x8*)&h[(size_t)s0 * 256 + cb];
        float e0 = v ? edge_alpha(als[(size_t)s0 * 2 + head] + dd) : 0.f;
        #pragma unroll
        for (int j = 0; j < 8; ++j) a[j] += e0 * (float)h0[j];
        den += e0;
    }
    #pragma unroll
    for (int j = 0; j < 8; ++j) a[j] += __shfl_xor(a[j], 32, 64);
    den += __shfl_xor(den, 32, 64);
    if (p == 0) {
        float inv = 1.f / den;
        f16x8 o;
        #pragma unroll
        for (int j = 0; j < 8; ++j) {
            float v = a[j] * inv + bias[cb + j];
            v = v > 0.f ? v : (__expf(v) - 1.f);
            o[j] = (f16)v;
        }
        *(f16x8*)&z[(size_t)n * 256 + cb] = o;
    }
}

// ------- layer-3 aggregate, fused alpha: 16 lanes/row (f16x8), 4 parities, 2x -------
__global__ __launch_bounds__(256) void k_agg3(const int* __restrict__ rowptr,
                                              const int* __restrict__ csr,
                                              const float* __restrict__ als,  // [n]
                                              const float* __restrict__ ald,  // [n]
                                              const f16* __restrict__ h,
                                              const float* __restrict__ bias,
                                              f16* __restrict__ z)
{
    int gid = blockIdx.x * 256 + threadIdx.x;
    int n = gid >> 6, lane = gid & 63;
    if (n >= NN) return;
    int p  = lane >> 4;
    int cb = (lane & 15) * 8;
    int r0 = rowptr[n], r1 = rowptr[n + 1];
    float dd = ald[n];
    float a[8] = {};
    float den = 0.f;
    int i = r0;
    for (; i + 8 <= r1; i += 8) {
        int i0 = i + p, i1 = i + 4 + p;
        int s0 = csr[i0], s1 = csr[i1];
        f16x8 h0 = *(const f16x8*)&h[(size_t)s0 * 128 + cb];
        f16x8 h1 = *(const f16x8*)&h[(size_t)s1 * 128 + cb];
        float e0 = edge_alpha(als[s0] + dd);
        float e1 = edge_alpha(als[s1] + dd);
        #pragma unroll
        for (int j = 0; j < 8; ++j)
            a[j] += e0 * (float)h0[j] + e1 * (float)h1[j];
        den += e0 + e1;
    }
    for (; i < r1; i += 4) {
        int ii = i + p;
        bool v = ii < r1;
        int s0 = csr[v ? ii : r0];
        f16x8 h0 = *(const f16x8*)&h[(size_t)s0 * 128 + cb];
        float e0 = v ? edge_alpha(als[s0] + dd) : 0.f;
        #pragma unroll
        for (int j = 0; j < 8; ++j) a[j] += e0 * (float)h0[j];
        den += e0;
    }
    #pragma unroll
    for (int j = 0; j < 8; ++j) {
        a[j] += __shfl_xor(a[j], 16, 64);
        a[j] += __shfl_xor(a[j], 32, 64);
    }
    den += __shfl_xor(den, 16, 64);
    den += __shfl_xor(den, 32, 64);
    if (lane < 16) {
        float inv = 1.f / den;
        f16x8 o;
        #pragma unroll
        for (int j = 0; j < 8; ++j)
            o[j] = (f16)(a[j] * inv + bias[cb + j]);
        *(f16x8*)&z[(size_t)n * 128 + cb] = o;
    }
}

// ---------- MFMA decoder: 64 edges/block, ef[64][256]f16 @ Wtl[64][256]^T ----------
#define DLDA 264
__global__ __launch_bounds__(256) void k_decm(const f16* __restrict__ z3,
                                              const int* __restrict__ eli,
                                              const int* __restrict__ ntypes,
                                              const f16* __restrict__ Wtl,  // [64][256]
                                              const float* __restrict__ bl1,
                                              const float* __restrict__ Wl2,
                                              const float* __restrict__ bl2,
                                              const float* __restrict__ tb,
                                              float* __restrict__ out)
{
    __shared__ f16 As[64 * DLDA];
    __shared__ int sls[64], sld[64];
    const int t = threadIdx.x;
    const int e0 = blockIdx.x * 64;
    if (t < 64) {
        int e = e0 + t;
        sls[t] = (e < ELN) ? eli[e] : 0;
        sld[t] = (e < ELN) ? eli[ELN + e] : 0;
    }
    __syncthreads();
    {
        int r = t & 63;
        int seg = t >> 6;
        int base = seg * 64;
        int node = (base < 128) ? sls[r] : sld[r];
        int zoff = base & 127;
        #pragma unroll
        for (int j = 0; j < 8; ++j) {
            f16x8 v = *(const f16x8*)&z3[(size_t)node * 128 + zoff + j * 8];
            *(f16x8*)&As[r * DLDA + base + j * 8] = v;
        }
    }
    __syncthreads();
    const int w = t >> 6;
    const int lane = t & 63;
    const int m = lane & 15;
    const int quad = lane >> 4;
    f32x4 acc[4] = {{0.f,0.f,0.f,0.f},{0.f,0.f,0.f,0.f},{0.f,0.f,0.f,0.f},{0.f,0.f,0.f,0.f}};
    for (int k0 = 0; k0 < 256; k0 += 32) {
        f16x8 af = *(const f16x8*)&As[(w * 16 + m) * DLDA + k0 + quad * 8];
        #pragma unroll
        for (int g = 0; g < 4; ++g) {
            f16x8 bf = *(const f16x8*)&Wtl[(size_t)(g * 16 + m) * 256 + k0 + quad * 8];
            acc[g] = __builtin_amdgcn_mfma_f32_16x16x32_f16(af, bf, acc[g], 0, 0, 0);
        }
    }
    float s[4] = {0.f, 0.f, 0.f, 0.f};
    #pragma unroll
    for (int g = 0; g < 4; ++g) {
        int col = g * 16 + m;
        float b = bl1[col], wv = Wl2[col];
        #pragma unroll
        for (int reg = 0; reg < 4; ++reg) {
            float hv = fmaxf(acc[g][reg] + b, 0.f);
            s[reg] += hv * wv;
        }
    }
    #pragma unroll
    for (int off = 1; off < 16; off <<= 1) {
        #pragma unroll
        for (int reg = 0; reg < 4; ++reg) s[reg] += __shfl_xor(s[reg], off, 64);
    }
    if (m == 0) {
        float b2v = bl2[0];
        #pragma unroll
        for (int reg = 0; reg < 4; ++reg) {
            int r = w * 16 + quad * 4 + reg;
            int e = e0 + r;
            if (e < ELN) {
                out[e] = s[reg] + b2v +
                         tb[(size_t)ntypes[sls[r]] * NT + ntypes[sld[r]]];
            }
        }
    }
}

// ---------------- launch ----------------
extern "C" void kernel_launch(void* const* d_in, const int* in_sizes, int n_in,
                              void* d_out, int out_size, void* d_ws, size_t ws_size,
                              hipStream_t stream)
{
    const float* x   = (const float*)d_in[0];
    const int*   ei  = (const int*)d_in[1];
    const int*   eli = (const int*)d_in[2];
    const float* emb = (const float*)d_in[3];
    const float* W1  = (const float*)d_in[4];
    const float* as1 = (const float*)d_in[5];
    const float* ad1 = (const float*)d_in[6];
    const float* b1  = (const float*)d_in[7];
    const float* W2  = (const float*)d_in[8];
    const float* as2 = (const float*)d_in[9];
    const float* ad2 = (const float*)d_in[10];
    const float* b2  = (const float*)d_in[11];
    const float* W3  = (const float*)d_in[12];
    const float* as3 = (const float*)d_in[13];
    const float* ad3 = (const float*)d_in[14];
    const float* b3  = (const float*)d_in[15];
    const float* Wl1 = (const float*)d_in[16];
    const float* bl1 = (const float*)d_in[17];
    const float* Wl2 = (const float*)d_in[18];
    const float* bl2 = (const float*)d_in[19];
    const float* tb  = (const float*)d_in[20];
    float* out = (float*)d_out;

    char* ws = (char*)d_ws;
    size_t off = 0;
    auto alloc = [&](size_t bytes) { size_t o = off; off = (off + bytes + 255) & ~(size_t)255; return o; };
    int*   ntypes = (int*)  (ws + alloc((size_t)NN * 4));
    f16*   xc16   = (f16*)  (ws + alloc((size_t)NN * 64 * 2));
    int*   rowptr = (int*)  (ws + alloc((size_t)(NN + 1) * 4));
    int*   csr    = (int*)  (ws + alloc((size_t)ETOT * 4));
    int*   bcur   = (int*)  (ws + alloc((size_t)(NBUCK + 1) * 4));
    int*   boff   = (int*)  (ws + alloc((size_t)(NBUCK + 1) * 4));
    // score buffers: [als1:4NN][ald1:4NN][als2:2NN][ald2:2NN][als3:NN][ald3:NN]
    float* scores = (float*)(ws + alloc((size_t)NN * 14 * 4));
    float* als1 = scores;
    float* ald1 = scores + (size_t)NN * 4;
    float* als2 = scores + (size_t)NN * 8;
    float* ald2 = scores + (size_t)NN * 10;
    float* als3 = scores + (size_t)NN * 12;
    float* ald3 = scores + (size_t)NN * 13;
    int2*  bbuf   = (int2*) (ws + alloc((size_t)NBUCK * BCAP * 8));
    f16*   h16    = (f16*)  (ws + alloc((size_t)NN * 256 * 2));   // also xagg
    f16*   z16    = (f16*)  (ws + alloc((size_t)NN * 256 * 2));
    f16*   Wt1    = (f16*)  (ws + alloc((size_t)4 * 64 * 64 * 2));
    f16*   Wt2    = (f16*)  (ws + alloc((size_t)256 * 256 * 2));
    f16*   Wt3    = (f16*)  (ws + alloc((size_t)128 * 256 * 2));
    f16*   Wtl    = (f16*)  (ws + alloc((size_t)64 * 256 * 2));
    float* a1ps   = (float*)(ws + alloc(256 * 4));
    float* a1pd   = (float*)(ws + alloc(256 * 4));

    hipMemsetAsync(bcur, 0, (size_t)(NBUCK + 1) * 4, stream);
    hipMemsetAsync(als2, 0, (size_t)NN * 6 * 4, stream);   // als2,ald2,als3,ald3

    const int RB   = (NN + 63) / 64;       // 782
    const int RB2  = (NN + 127) / 128;     // 391
    const int gW1  = (NN + 3) / 4;         // 1 wave/node

    k_pre1<<<1, 256, 0, stream>>>(W1, as1, ad1, a1ps, a1pd);
    k_prepatt<<<gW1, 256, 0, stream>>>(x, emb, a1ps, a1pd, xc16, ntypes, als1, ald1);
    k_cvtall<<<(131072 + 255) / 256, 256, 0, stream>>>(W1, W2, W3, Wl1, Wt1, Wt2, Wt3, Wtl);

    // CSR build: bucket scatter -> bucket scan -> per-bucket counting sort
    k_bucket<<<(ETOT + CHUNK - 1) / CHUNK, 256, 0, stream>>>(ei, bcur, bbuf);
    k_bscan <<<1, 512, 0, stream>>>(bcur, boff);
    k_csrb  <<<NBUCK, 256, 0, stream>>>(bcur, boff, bbuf, rowptr, csr);

    // Layer 1 (linearity-swapped; scores from k_prepatt; alpha fused in agg)
    k_aggx<<<gW1, 256, 0, stream>>>(rowptr, csr, als1, ald1, xc16, h16 /*xagg*/);
    k_gemm1h<<<dim3(RB, 4), 256, 0, stream>>>(h16 /*xagg*/, Wt1, b1, z16, NN);

    // Layer 2 (att fused into 128x128 GEMM epilogue; alpha fused in agg)
    k_gemmw<256, 256, 2><<<dim3(RB2, 2), 256, 0, stream>>>(z16, Wt2, h16, NN, as2, ad2, als2, ald2);
    k_agg2f<<<gW1, 256, 0, stream>>>(rowptr, csr, als2, ald2, h16, b2, z16);

    // Layer 3 (att fused into 128x128 GEMM epilogue; alpha fused in agg)
    k_gemmw<256, 128, 1><<<dim3(RB2, 1), 256, 0, stream>>>(z16, Wt3, h16, NN, as3, ad3, als3, ald3);
    k_agg3<<<gW1, 256, 0, stream>>>(rowptr, csr, als3, ald3, h16, b3, z16);

    // Decoder (MFMA)
    k_decm<<<(ELN + 63) / 64, 256, 0, stream>>>(z16, eli, ntypes, Wtl, bl1, Wl2, bl2, tb, out);
}

// Round 7
// 388.749 us; speedup vs baseline: 2.1503x; 1.0218x over previous
//
#include <hip/hip_runtime.h>
#include <hip/hip_bf16.h>

#define NN 50000
#define EE 800000
#define ELN 100000
#define ETOT (EE + NN)
#define NT 311

// ---- bucketed CSR build params ----
#define NBUCK ((NN + 127) >> 7)     // 391 buckets of 128 nodes
#define BCAP 3072                   // capacity per bucket (mean 2174, ~19 sigma margin)
#define CHUNK 8192                  // edges per k_bucket block

// ---- k_setup block ranges ----
#define SB_CVT 512                              // 131072/256 conversion blocks
#define SB_PRE (SB_CVT)                         // 1 block: pre1
#define SB_BC  (SB_CVT + 1)                     // 1 block: zero bcur
#define SB_ZS  (SB_CVT + 2)                     // first score-zero block
#define ZS_N   (NN * 6)                         // floats to zero
#define SB_TOT (SB_ZS + (ZS_N + 255) / 256)

typedef _Float16 f16;
typedef f16 f16x8 __attribute__((ext_vector_type(8)));
typedef f16 f16x4 __attribute__((ext_vector_type(4)));
typedef f16 f16x2 __attribute__((ext_vector_type(2)));
typedef float f32x4 __attribute__((ext_vector_type(4)));

__device__ __forceinline__ float edge_alpha(float l)
{
    l = l > 0.f ? l : 0.2f * l;
    return __expf(fminf(l, 80.f));
}

// ------- fused prep + layer-1 att scores: one wave per node -------
__global__ __launch_bounds__(256) void k_prepatt(const float* __restrict__ x,
                                                 const float* __restrict__ emb,
                                                 const float* __restrict__ a1ps,
                                                 const float* __restrict__ a1pd,
                                                 f16* __restrict__ xc,
                                                 int* __restrict__ ntypes,
                                                 float* __restrict__ als,
                                                 float* __restrict__ ald)
{
    int gid = blockIdx.x * 256 + threadIdx.x;
    int n = gid >> 6, lane = gid & 63;
    if (n >= NN) return;
    int tpe = (int)x[(size_t)n * 33];
    tpe = tpe < 0 ? 0 : (tpe > NT - 1 ? NT - 1 : tpe);
    if (lane == 0) ntypes[n] = tpe;
    float v;
    if (lane < 16)      v = emb[tpe * 16 + lane];
    else if (lane < 48) v = x[(size_t)n * 33 + 1 + (lane - 16)];
    else                v = 0.f;
    f16 hv = (f16)v;
    xc[(size_t)n * 64 + lane] = hv;
    float xv = (float)hv;
    float ps[4], pd[4];
    #pragma unroll
    for (int h = 0; h < 4; ++h) {
        ps[h] = xv * a1ps[h * 64 + lane];
        pd[h] = xv * a1pd[h * 64 + lane];
    }
    #pragma unroll
    for (int off = 32; off > 0; off >>= 1) {
        #pragma unroll
        for (int h = 0; h < 4; ++h) {
            ps[h] += __shfl_xor(ps[h], off, 64);
            pd[h] += __shfl_xor(pd[h], off, 64);
        }
    }
    if (lane == 0) {
        #pragma unroll
        for (int h = 0; h < 4; ++h) {
            als[n * 4 + h] = ps[h];
            ald[n * 4 + h] = pd[h];
        }
    }
}

// ---- fused setup: weight conversions + a-fold + bcur zero + score zero ----
__global__ __launch_bounds__(256) void k_setup(const float* __restrict__ W1,
                                               const float* __restrict__ W2,
                                               const float* __restrict__ W3,
                                               const float* __restrict__ Wl1,
                                               f16* __restrict__ Wt1,
                                               f16* __restrict__ Wt2,
                                               f16* __restrict__ Wt3,
                                               f16* __restrict__ Wtl,
                                               const float* __restrict__ as1,
                                               const float* __restrict__ ad1,
                                               float* __restrict__ a1ps,
                                               float* __restrict__ a1pd,
                                               int* __restrict__ bcur,
                                               float* __restrict__ zsc)
{
    const int b = blockIdx.x;
    const int t = threadIdx.x;
    if (b < SB_CVT) {
        int idx = b * 256 + t;
        if (idx < 16384) {
            int h = idx >> 12, c = (idx >> 6) & 63, k = idx & 63;
            Wt1[idx] = (k < 48) ? (f16)W1[(size_t)k * 256 + h * 64 + c] : (f16)0.f;
        } else if (idx < 81920) {
            int i = idx - 16384;
            int c = i >> 8, k = i & 255;
            Wt2[i] = (f16)W2[(size_t)k * 256 + c];
        } else if (idx < 114688) {
            int i = idx - 81920;
            int c = i >> 8, k = i & 255;
            Wt3[i] = (f16)W3[(size_t)k * 128 + c];
        } else {
            int i = idx - 114688;
            int c = i >> 8, k = i & 255;
            Wtl[i] = (f16)Wl1[(size_t)k * 64 + c];
        }
    } else if (b == SB_PRE) {
        int h = t >> 6, k = t & 63;
        float ss = 0.f, sd = 0.f;
        if (k < 48) {
            for (int d = 0; d < 64; ++d) {
                float w = W1[(size_t)k * 256 + h * 64 + d];
                ss += w * as1[h * 64 + d];
                sd += w * ad1[h * 64 + d];
            }
        }
        a1ps[t] = ss;
        a1pd[t] = sd;
    } else if (b == SB_BC) {
        for (int i = t; i < NBUCK + 1; i += 256) bcur[i] = 0;
    } else {
        int i = (b - SB_ZS) * 256 + t;
        if (i < ZS_N) zsc[i] = 0.f;
    }
}

// ---------------- bucketed CSR build ----------------
__global__ __launch_bounds__(256) void k_bucket(const int* __restrict__ ei,
                                                int* __restrict__ bcur,
                                                int2* __restrict__ bbuf)
{
    __shared__ int hist[NBUCK];
    __shared__ int gbase[NBUCK];
    const int t = threadIdx.x;
    for (int i = t; i < NBUCK; i += 256) hist[i] = 0;
    __syncthreads();
    const int e0 = blockIdx.x * CHUNK;
    const int eend = min(e0 + CHUNK, ETOT);
    for (int e = e0 + t; e < eend; e += 256) {
        int dst = (e < EE) ? ei[EE + e] : (e - EE);
        atomicAdd(&hist[dst >> 7], 1);
    }
    __syncthreads();
    for (int i = t; i < NBUCK; i += 256) {
        int c = hist[i];
        gbase[i] = c ? atomicAdd(&bcur[i], c) : 0;
        hist[i] = 0;     // reuse as local cursor
    }
    __syncthreads();
    for (int e = e0 + t; e < eend; e += 256) {
        int src, dst;
        if (e < EE) { src = ei[e]; dst = ei[EE + e]; }
        else        { src = e - EE; dst = src; }
        int b = dst >> 7;
        int pos = gbase[b] + atomicAdd(&hist[b], 1);
        if (pos < BCAP)
            bbuf[(size_t)b * BCAP + pos] = make_int2(src, dst);
    }
}

// One block per bucket. Computes its own global base (reduction over bcur),
// LDS counting sort by exact dst, emits rowptr directly, writes csr coalesced.
__global__ __launch_bounds__(256) void k_csrb(const int* __restrict__ bcur,
                                              const int2* __restrict__ bbuf,
                                              int* __restrict__ rowptr,
                                              int* __restrict__ csr)
{
    __shared__ int red[256];
    __shared__ int nh[128];     // per-node hist -> inclusive prefix
    __shared__ int loff[128];   // per-node exclusive local offset
    __shared__ int ncur[128];
    __shared__ int ssrc[BCAP];
    const int b = blockIdx.x;
    const int t = threadIdx.x;
    const int n0 = b << 7;
    const int cnt = min(bcur[b], BCAP);
    const size_t bb = (size_t)b * BCAP;
    // base = sum of min(bcur[j],BCAP) for j < b; block 0 also needs total
    int accb = 0, acct = 0;
    for (int j = t; j < NBUCK; j += 256) {
        int c = min(bcur[j], BCAP);
        acct += c;
        if (j < b) accb += c;
    }
    red[t] = accb;
    __syncthreads();
    #pragma unroll
    for (int off = 128; off > 0; off >>= 1) {
        if (t < off) red[t] += red[t + off];
        __syncthreads();
    }
    const int base = red[0];
    __syncthreads();
    if (b == 0) {
        red[t] = acct;
        __syncthreads();
        #pragma unroll
        for (int off = 128; off > 0; off >>= 1) {
            if (t < off) red[t] += red[t + off];
            __syncthreads();
        }
        if (t == 0) rowptr[NN] = red[0];
        __syncthreads();
    }
    if (t < 128) { nh[t] = 0; ncur[t] = 0; }
    __syncthreads();
    for (int i = t; i < cnt; i += 256)
        atomicAdd(&nh[bbuf[bb + i].y - n0], 1);
    __syncthreads();
    int myc = (t < 128) ? nh[t] : 0;
    #pragma unroll
    for (int off = 1; off < 128; off <<= 1) {
        int u = (t >= off && t < 128) ? nh[t - off] : 0;
        __syncthreads();
        if (t < 128) nh[t] += u;
        __syncthreads();
    }
    if (t < 128) {
        int ex = nh[t] - myc;
        loff[t] = ex;
        int n = n0 + t;
        if (n < NN) rowptr[n] = base + ex;
    }
    __syncthreads();
    for (int i = t; i < cnt; i += 256) {
        int2 p = bbuf[bb + i];
        int ln = p.y - n0;
        int pos = loff[ln] + atomicAdd(&ncur[ln], 1);
        ssrc[pos] = p.x;
    }
    __syncthreads();
    for (int i = t; i < cnt; i += 256)
        csr[base + i] = ssrc[i];
}

// ------- MFMA f16 GEMM, 128x128 tile, optional fused attention-score partials -------
template<int K, int CN, int H>
__global__ __launch_bounds__(256) void k_gemmw(const f16* __restrict__ A,
                                               const f16* __restrict__ Wt,
                                               f16* __restrict__ O,
                                               int nrows,
                                               const float* __restrict__ asrc,
                                               const float* __restrict__ adst,
                                               float* __restrict__ als,
                                               float* __restrict__ ald)
{
    constexpr int LDK = 40;
    __shared__ f16 As[128 * LDK];
    __shared__ f16 Bs[128 * LDK];
    const int t = threadIdx.x;
    const int w = t >> 6;
    const int lane = t & 63;
    const int m = lane & 15;
    const int quad = lane >> 4;
    const int row0 = blockIdx.x * 128;
    const int col0 = blockIdx.y * 128;
    const int r_st = t >> 1;        // 0..127: one row per thread-pair
    const int seg  = (t & 1) * 16;  // halves 0..15 or 16..31
    f32x4 acc[2][8] = {};
    for (int k0 = 0; k0 < K; k0 += 32) {
        int gr = row0 + r_st;
        f16x8 av0 = {0,0,0,0,0,0,0,0}, av1 = {0,0,0,0,0,0,0,0};
        if (gr < nrows) {
            av0 = *(const f16x8*)&A[(size_t)gr * K + k0 + seg];
            av1 = *(const f16x8*)&A[(size_t)gr * K + k0 + seg + 8];
        }
        *(f16x8*)&As[r_st * LDK + seg]     = av0;
        *(f16x8*)&As[r_st * LDK + seg + 8] = av1;
        f16x8 bv0 = *(const f16x8*)&Wt[(size_t)(col0 + r_st) * K + k0 + seg];
        f16x8 bv1 = *(const f16x8*)&Wt[(size_t)(col0 + r_st) * K + k0 + seg + 8];
        *(f16x8*)&Bs[r_st * LDK + seg]     = bv0;
        *(f16x8*)&Bs[r_st * LDK + seg + 8] = bv1;
        __syncthreads();
        f16x8 af0 = *(const f16x8*)&As[(w * 32 + m) * LDK + quad * 8];
        f16x8 af1 = *(const f16x8*)&As[(w * 32 + 16 + m) * LDK + quad * 8];
        #pragma unroll
        for (int g = 0; g < 8; ++g) {
            f16x8 bf = *(const f16x8*)&Bs[(g * 16 + m) * LDK + quad * 8];
            acc[0][g] = __builtin_amdgcn_mfma_f32_16x16x32_f16(af0, bf, acc[0][g], 0, 0, 0);
            acc[1][g] = __builtin_amdgcn_mfma_f32_16x16x32_f16(af1, bf, acc[1][g], 0, 0, 0);
        }
        __syncthreads();
    }
    #pragma unroll
    for (int rb = 0; rb < 2; ++rb) {
        #pragma unroll
        for (int g = 0; g < 8; ++g) {
            #pragma unroll
            for (int reg = 0; reg < 4; ++reg) {
                int gr = row0 + w * 32 + rb * 16 + quad * 4 + reg;
                int gc = col0 + g * 16 + m;
                if (gr < nrows) O[(size_t)gr * CN + gc] = (f16)acc[rb][g][reg];
            }
        }
    }
    if constexpr (H > 0) {
        constexpr int D = CN / H;
        const int head = col0 / D;   // col tile = 128 = one head
        float ps[2][4] = {}, pd[2][4] = {};
        #pragma unroll
        for (int g = 0; g < 8; ++g) {
            int col = col0 + g * 16 + m;
            float a_s = asrc[col], a_d = adst[col];
            #pragma unroll
            for (int rb = 0; rb < 2; ++rb) {
                #pragma unroll
                for (int reg = 0; reg < 4; ++reg) {
                    ps[rb][reg] += acc[rb][g][reg] * a_s;
                    pd[rb][reg] += acc[rb][g][reg] * a_d;
                }
            }
        }
        #pragma unroll
        for (int off = 1; off < 16; off <<= 1) {
            #pragma unroll
            for (int rb = 0; rb < 2; ++rb) {
                #pragma unroll
                for (int reg = 0; reg < 4; ++reg) {
                    ps[rb][reg] += __shfl_xor(ps[rb][reg], off, 64);
                    pd[rb][reg] += __shfl_xor(pd[rb][reg], off, 64);
                }
            }
        }
        if (m == 0) {
            #pragma unroll
            for (int rb = 0; rb < 2; ++rb) {
                #pragma unroll
                for (int reg = 0; reg < 4; ++reg) {
                    int gr = row0 + w * 32 + rb * 16 + quad * 4 + reg;
                    if (gr < nrows) {
                        atomicAdd(&als[gr * H + head], ps[rb][reg]);
                        atomicAdd(&ald[gr * H + head], pd[rb][reg]);
                    }
                }
            }
        }
    }
}

// ----- layer-1 per-head GEMM with fused bias+ELU -----
__global__ __launch_bounds__(256) void k_gemm1h(const f16* __restrict__ A,
                                                const f16* __restrict__ Wt1,
                                                const float* __restrict__ bias,
                                                f16* __restrict__ O,
                                                int nrows)
{
    constexpr int LDA = 40;
    __shared__ f16 As[64 * LDA];
    __shared__ f16 Bs[64 * LDA];
    const int t = threadIdx.x;
    const int w = t >> 6;
    const int lane = t & 63;
    const int m = lane & 15;
    const int quad = lane >> 4;
    const int row0 = blockIdx.x * 64;
    const int head = blockIdx.y;
    const int r_st = t >> 2;
    const int seg  = (t & 3) * 8;
    f32x4 acc[4] = {{0.f,0.f,0.f,0.f},{0.f,0.f,0.f,0.f},{0.f,0.f,0.f,0.f},{0.f,0.f,0.f,0.f}};
    for (int k0 = 0; k0 < 64; k0 += 32) {
        int gr = row0 + r_st;
        f16x8 av = {0,0,0,0,0,0,0,0};
        if (gr < nrows) av = *(const f16x8*)&A[(size_t)gr * 256 + head * 64 + k0 + seg];
        *(f16x8*)&As[r_st * LDA + seg] = av;
        f16x8 bv = *(const f16x8*)&Wt1[(size_t)head * 4096 + (size_t)r_st * 64 + k0 + seg];
        *(f16x8*)&Bs[r_st * LDA + seg] = bv;
        __syncthreads();
        f16x8 af = *(const f16x8*)&As[(w * 16 + m) * LDA + quad * 8];
        #pragma unroll
        for (int g = 0; g < 4; ++g) {
            f16x8 bf = *(const f16x8*)&Bs[(g * 16 + m) * LDA + quad * 8];
            acc[g] = __builtin_amdgcn_mfma_f32_16x16x32_f16(af, bf, acc[g], 0, 0, 0);
        }
        __syncthreads();
    }
    #pragma unroll
    for (int g = 0; g < 4; ++g) {
        #pragma unroll
        for (int reg = 0; reg < 4; ++reg) {
            int gr = row0 + w * 16 + quad * 4 + reg;
            int col = head * 64 + g * 16 + m;
            if (gr < nrows) {
                float v = acc[g][reg] + bias[col];
                v = v > 0.f ? v : (__expf(v) - 1.f);
                O[(size_t)gr * 256 + col] = (f16)v;
            }
        }
    }
}

// ------- layer-1 aggregate over xc, fused alpha: 4 parities x 16 lanes, f16x4 -------
__global__ __launch_bounds__(256) void k_aggx(const int* __restrict__ rowptr,
                                              const int* __restrict__ csr,
                                              const float* __restrict__ als,  // [n][4]
                                              const float* __restrict__ ald,  // [n][4]
                                              const f16* __restrict__ xc,
                                              f16* __restrict__ xagg)
{
    int gid = blockIdx.x * 256 + threadIdx.x;
    int n = gid >> 6, lane = gid & 63;
    if (n >= NN) return;
    int p  = lane >> 4;        // 4 edge parities
    int fl = lane & 15;        // 16 feature lanes
    int cb = fl * 4;           // 4 feats per lane
    int r0 = rowptr[n], r1 = rowptr[n + 1];
    float4 dl = *(const float4*)&ald[(size_t)n * 4];
    float a0[4] = {}, a1[4] = {}, a2[4] = {}, a3[4] = {};
    float d0 = 0.f, d1 = 0.f, d2 = 0.f, d3 = 0.f;
    int i = r0;
    for (; i + 8 <= r1; i += 8) {
        int i0 = i + p, i1 = i + 4 + p;
        int s0 = csr[i0], s1 = csr[i1];
        f16x4 x0 = *(const f16x4*)&xc[(size_t)s0 * 64 + cb];
        f16x4 x1 = *(const f16x4*)&xc[(size_t)s1 * 64 + cb];
        float4 A0 = *(const float4*)&als[(size_t)s0 * 4];
        float4 A1 = *(const float4*)&als[(size_t)s1 * 4];
        float4 e0, e1;
        e0.x = edge_alpha(A0.x + dl.x); e1.x = edge_alpha(A1.x + dl.x);
        e0.y = edge_alpha(A0.y + dl.y); e1.y = edge_alpha(A1.y + dl.y);
        e0.z = edge_alpha(A0.z + dl.z); e1.z = edge_alpha(A1.z + dl.z);
        e0.w = edge_alpha(A0.w + dl.w); e1.w = edge_alpha(A1.w + dl.w);
        #pragma unroll
        for (int j = 0; j < 4; ++j) {
            float v0 = (float)x0[j], v1 = (float)x1[j];
            a0[j] += e0.x * v0 + e1.x * v1;
            a1[j] += e0.y * v0 + e1.y * v1;
            a2[j] += e0.z * v0 + e1.z * v1;
            a3[j] += e0.w * v0 + e1.w * v1;
        }
        d0 += e0.x + e1.x; d1 += e0.y + e1.y;
        d2 += e0.z + e1.z; d3 += e0.w + e1.w;
    }
    for (; i < r1; i += 4) {
        int ii = i + p;
        bool v = ii < r1;
        int s0 = csr[v ? ii : r0];
        f16x4 x0 = *(const f16x4*)&xc[(size_t)s0 * 64 + cb];
        float4 A0 = *(const float4*)&als[(size_t)s0 * 4];
        float4 e0;
        e0.x = v ? edge_alpha(A0.x + dl.x) : 0.f;
        e0.y = v ? edge_alpha(A0.y + dl.y) : 0.f;
        e0.z = v ? edge_alpha(A0.z + dl.z) : 0.f;
        e0.w = v ? edge_alpha(A0.w + dl.w) : 0.f;
        #pragma unroll
        for (int j = 0; j < 4; ++j) {
            float v0 = (float)x0[j];
            a0[j] += e0.x * v0; a1[j] += e0.y * v0;
            a2[j] += e0.z * v0; a3[j] += e0.w * v0;
        }
        d0 += e0.x; d1 += e0.y; d2 += e0.z; d3 += e0.w;
    }
    #pragma unroll
    for (int off = 16; off < 64; off <<= 1) {
        #pragma unroll
        for (int j = 0; j < 4; ++j) {
            a0[j] += __shfl_xor(a0[j], off, 64);
            a1[j] += __shfl_xor(a1[j], off, 64);
            a2[j] += __shfl_xor(a2[j], off, 64);
            a3[j] += __shfl_xor(a3[j], off, 64);
        }
        d0 += __shfl_xor(d0, off, 64);
        d1 += __shfl_xor(d1, off, 64);
        d2 += __shfl_xor(d2, off, 64);
        d3 += __shfl_xor(d3, off, 64);
    }
    if (p == 0) {
        float i0 = 1.f / d0, i1 = 1.f / d1, i2 = 1.f / d2, i3 = 1.f / d3;
        size_t base = (size_t)n * 256 + cb;
        f16x4 o0, o1, o2, o3;
        #pragma unroll
        for (int j = 0; j < 4; ++j) {
            o0[j] = (f16)(a0[j] * i0);
            o1[j] = (f16)(a1[j] * i1);
            o2[j] = (f16)(a2[j] * i2);
            o3[j] = (f16)(a3[j] * i3);
        }
        *(f16x4*)&xagg[base]       = o0;
        *(f16x4*)&xagg[base + 64]  = o1;
        *(f16x4*)&xagg[base + 128] = o2;
        *(f16x4*)&xagg[base + 192] = o3;
    }
}

// ------- layer-2 aggregate, fused alpha: 32 lanes/row (f16x8), 2 parities, 4x -------
__global__ __launch_bounds__(256) void k_agg2f(const int* __restrict__ rowptr,
                                               const int* __restrict__ csr,
                                               const float* __restrict__ als,  // [n][2]
                                               const float* __restrict__ ald,  // [n][2]
                                               const f16* __restrict__ h,
                                               const float* __restrict__ bias,
                                               f16* __restrict__ z)
{
    int gid = blockIdx.x * 256 + threadIdx.x;
    int n = gid >> 6, lane = gid & 63;
    if (n >= NN) return;
    int p  = lane >> 5;
    int cb = (lane & 31) * 8;
    int head = cb >> 7;
    int r0 = rowptr[n], r1 = rowptr[n + 1];
    float dd = ald[(size_t)n * 2 + head];
    float a[8] = {};
    float den = 0.f;
    int i = r0;
    for (; i + 8 <= r1; i += 8) {
        int i0 = i + p, i1 = i + 2 + p, i2 = i + 4 + p, i3 = i + 6 + p;
        int s0 = csr[i0], s1 = csr[i1], s2 = csr[i2], s3 = csr[i3];
        f16x8 h0 = *(const f16x8*)&h[(size_t)s0 * 256 + cb];
        f16x8 h1 = *(const f16x8*)&h[(size_t)s1 * 256 + cb];
        f16x8 h2 = *(const f16x8*)&h[(size_t)s2 * 256 + cb];
        f16x8 h3 = *(const f16x8*)&h[(size_t)s3 * 256 + cb];
        float w0 = als[(size_t)s0 * 2 + head];
        float w1 = als[(size_t)s1 * 2 + head];
        float w2 = als[(size_t)s2 * 2 + head];
        float w3 = als[(size_t)s3 * 2 + head];
        float e0 = edge_alpha(w0 + dd);
        float e1 = edge_alpha(w1 + dd);
        float e2 = edge_alpha(w2 + dd);
        float e3 = edge_alpha(w3 + dd);
        #pragma unroll
        for (int j = 0; j < 8; ++j)
            a[j] += e0 * (float)h0[j] + e1 * (float)h1[j]
                  + e2 * (float)h2[j] + e3 * (float)h3[j];
        den += e0 + e1 + e2 + e3;
    }
    for (; i < r1; i += 2) {
        int ii = i + p;
        bool v = ii < r1;
        int s0 = csr[v ? ii : r0];
        f16x8 h0 = *(const f16x8*)&h[(size_t)s0 * 256 + cb];
        float e0 = v ? edge_alpha(als[(size_t)s0 * 2 + head] + dd) : 0.f;
        #pragma unroll
        for (int j = 0; j < 8; ++j) a[j] += e0 * (float)h0[j];
        den += e0;
    }
    #pragma unroll
    for (int j = 0; j < 8; ++j) a[j] += __shfl_xor(a[j], 32, 64);
    den += __shfl_xor(den, 32, 64);
    if (p == 0) {
        float inv = 1.f / den;
        f16x8 o;
        #pragma unroll
        for (int j = 0; j < 8; ++j) {
            float v = a[j] * inv + bias[cb + j];
            v = v > 0.f ? v : (__expf(v) - 1.f);
            o[j] = (f16)v;
        }
        *(f16x8*)&z[(size_t)n * 256 + cb] = o;
    }
}

// ------- layer-3 aggregate, fused alpha: 16 lanes/row (f16x8), 4 parities, 2x -------
__global__ __launch_bounds__(256) void k_agg3(const int* __restrict__ rowptr,
                                              const int* __restrict__ csr,
                                              const float* __restrict__ als,  // [n]
                                              const float* __restrict__ ald,  // [n]
                                              const f16* __restrict__ h,
                                              const float* __restrict__ bias,
                                              f16* __restrict__ z)
{
    int gid = blockIdx.x * 256 + threadIdx.x;
    int n = gid >> 6, lane = gid & 63;
    if (n >= NN) return;
    int p  = lane >> 4;
    int cb = (lane & 15) * 8;
    int r0 = rowptr[n], r1 = rowptr[n + 1];
    float dd = ald[n];
    float a[8] = {};
    float den = 0.f;
    int i = r0;
    for (; i + 8 <= r1; i += 8) {
        int i0 = i + p, i1 = i + 4 + p;
        int s0 = csr[i0], s1 = csr[i1];
        f16x8 h0 = *(const f16x8*)&h[(size_t)s0 * 128 + cb];
        f16x8 h1 = *(const f16x8*)&h[(size_t)s1 * 128 + cb];
        float e0 = edge_alpha(als[s0] + dd);
        float e1 = edge_alpha(als[s1] + dd);
        #pragma unroll
        for (int j = 0; j < 8; ++j)
            a[j] += e0 * (float)h0[j] + e1 * (float)h1[j];
        den += e0 + e1;
    }
    for (; i < r1; i += 4) {
        int ii = i + p;
        bool v = ii < r1;
        int s0 = csr[v ? ii : r0];
        f16x8 h0 = *(const f16x8*)&h[(size_t)s0 * 128 + cb];
        float e0 = v ? edge_alpha(als[s0] + dd) : 0.f;
        #pragma unroll
        for (int j = 0; j < 8; ++j) a[j] += e0 * (float)h0[j];
        den += e0;
    }
    #pragma unroll
    for (int j = 0; j < 8; ++j) {
        a[j] += __shfl_xor(a[j], 16, 64);
        a[j] += __shfl_xor(a[j], 32, 64);
    }
    den += __shfl_xor(den, 16, 64);
    den += __shfl_xor(den, 32, 64);
    if (lane < 16) {
        float inv = 1.f / den;
        f16x8 o;
        #pragma unroll
        for (int j = 0; j < 8; ++j)
            o[j] = (f16)(a[j] * inv + bias[cb + j]);
        *(f16x8*)&z[(size_t)n * 128 + cb] = o;
    }
}

// ---------- MFMA decoder: 64 edges/block, ef[64][256]f16 @ Wtl[64][256]^T ----------
#define DLDA 264
__global__ __launch_bounds__(256) void k_decm(const f16* __restrict__ z3,
                                              const int* __restrict__ eli,
                                              const int* __restrict__ ntypes,
                                              const f16* __restrict__ Wtl,  // [64][256]
                                              const float* __restrict__ bl1,
                                              const float* __restrict__ Wl2,
                                              const float* __restrict__ bl2,
                                              const float* __restrict__ tb,
                                              float* __restrict__ out)
{
    __shared__ f16 As[64 * DLDA];
    __shared__ int sls[64], sld[64];
    const int t = threadIdx.x;
    const int e0 = blockIdx.x * 64;
    if (t < 64) {
        int e = e0 + t;
        sls[t] = (e < ELN) ? eli[e] : 0;
        sld[t] = (e < ELN) ? eli[ELN + e] : 0;
    }
    __syncthreads();
    {
        int r = t & 63;
        int seg = t >> 6;
        int base = seg * 64;
        int node = (base < 128) ? sls[r] : sld[r];
        int zoff = base & 127;
        #pragma unroll
        for (int j = 0; j < 8; ++j) {
            f16x8 v = *(const f16x8*)&z3[(size_t)node * 128 + zoff + j * 8];
            *(f16x8*)&As[r * DLDA + base + j * 8] = v;
        }
    }
    __syncthreads();
    const int w = t >> 6;
    const int lane = t & 63;
    const int m = lane & 15;
    const int quad = lane >> 4;
    f32x4 acc[4] = {{0.f,0.f,0.f,0.f},{0.f,0.f,0.f,0.f},{0.f,0.f,0.f,0.f},{0.f,0.f,0.f,0.f}};
    for (int k0 = 0; k0 < 256; k0 += 32) {
        f16x8 af = *(const f16x8*)&As[(w * 16 + m) * DLDA + k0 + quad * 8];
        #pragma unroll
        for (int g = 0; g < 4; ++g) {
            f16x8 bf = *(const f16x8*)&Wtl[(size_t)(g * 16 + m) * 256 + k0 + quad * 8];
            acc[g] = __builtin_amdgcn_mfma_f32_16x16x32_f16(af, bf, acc[g], 0, 0, 0);
        }
    }
    float s[4] = {0.f, 0.f, 0.f, 0.f};
    #pragma unroll
    for (int g = 0; g < 4; ++g) {
        int col = g * 16 + m;
        float b = bl1[col], wv = Wl2[col];
        #pragma unroll
        for (int reg = 0; reg < 4; ++reg) {
            float hv = fmaxf(acc[g][reg] + b, 0.f);
            s[reg] += hv * wv;
        }
    }
    #pragma unroll
    for (int off = 1; off < 16; off <<= 1) {
        #pragma unroll
        for (int reg = 0; reg < 4; ++reg) s[reg] += __shfl_xor(s[reg], off, 64);
    }
    if (m == 0) {
        float b2v = bl2[0];
        #pragma unroll
        for (int reg = 0; reg < 4; ++reg) {
            int r = w * 16 + quad * 4 + reg;
            int e = e0 + r;
            if (e < ELN) {
                out[e] = s[reg] + b2v +
                         tb[(size_t)ntypes[sls[r]] * NT + ntypes[sld[r]]];
            }
        }
    }
}

// ---------------- launch ----------------
extern "C" void kernel_launch(void* const* d_in, const int* in_sizes, int n_in,
                              void* d_out, int out_size, void* d_ws, size_t ws_size,
                              hipStream_t stream)
{
    const float* x   = (const float*)d_in[0];
    const int*   ei  = (const int*)d_in[1];
    const int*   eli = (const int*)d_in[2];
    const float* emb = (const float*)d_in[3];
    const float* W1  = (const float*)d_in[4];
    const float* as1 = (const float*)d_in[5];
    const float* ad1 = (const float*)d_in[6];
    const float* b1  = (const float*)d_in[7];
    const float* W2  = (const float*)d_in[8];
    const float* as2 = (const float*)d_in[9];
    const float* ad2 = (const float*)d_in[10];
    const float* b2  = (const float*)d_in[11];
    const float* W3  = (const float*)d_in[12];
    const float* as3 = (const float*)d_in[13];
    const float* ad3 = (const float*)d_in[14];
    const float* b3  = (const float*)d_in[15];
    const float* Wl1 = (const float*)d_in[16];
    const float* bl1 = (const float*)d_in[17];
    const float* Wl2 = (const float*)d_in[18];
    const float* bl2 = (const float*)d_in[19];
    const float* tb  = (const float*)d_in[20];
    float* out = (float*)d_out;

    char* ws = (char*)d_ws;
    size_t off = 0;
    auto alloc = [&](size_t bytes) { size_t o = off; off = (off + bytes + 255) & ~(size_t)255; return o; };
    int*   ntypes = (int*)  (ws + alloc((size_t)NN * 4));
    f16*   xc16   = (f16*)  (ws + alloc((size_t)NN * 64 * 2));
    int*   rowptr = (int*)  (ws + alloc((size_t)(NN + 1) * 4));
    int*   csr    = (int*)  (ws + alloc((size_t)ETOT * 4));
    int*   bcur   = (int*)  (ws + alloc((size_t)(NBUCK + 1) * 4));
    // score buffers: [als1:4NN][ald1:4NN][als2:2NN][ald2:2NN][als3:NN][ald3:NN]
    float* scores = (float*)(ws + alloc((size_t)NN * 14 * 4));
    float* als1 = scores;
    float* ald1 = scores + (size_t)NN * 4;
    float* als2 = scores + (size_t)NN * 8;
    float* ald2 = scores + (size_t)NN * 10;
    float* als3 = scores + (size_t)NN * 12;
    float* ald3 = scores + (size_t)NN * 13;
    int2*  bbuf   = (int2*) (ws + alloc((size_t)NBUCK * BCAP * 8));
    f16*   h16    = (f16*)  (ws + alloc((size_t)NN * 256 * 2));   // also xagg
    f16*   z16    = (f16*)  (ws + alloc((size_t)NN * 256 * 2));
    f16*   Wt1    = (f16*)  (ws + alloc((size_t)4 * 64 * 64 * 2));
    f16*   Wt2    = (f16*)  (ws + alloc((size_t)256 * 256 * 2));
    f16*   Wt3    = (f16*)  (ws + alloc((size_t)128 * 256 * 2));
    f16*   Wtl    = (f16*)  (ws + alloc((size_t)64 * 256 * 2));
    float* a1ps   = (float*)(ws + alloc(256 * 4));
    float* a1pd   = (float*)(ws + alloc(256 * 4));

    const int RB   = (NN + 63) / 64;       // 782
    const int RB2  = (NN + 127) / 128;     // 391
    const int gW1  = (NN + 3) / 4;         // 1 wave/node

    // setup: weight cvt + a1-fold + bcur zero + score-buffer zero (one launch)
    k_setup<<<SB_TOT, 256, 0, stream>>>(W1, W2, W3, Wl1, Wt1, Wt2, Wt3, Wtl,
                                        as1, ad1, a1ps, a1pd, bcur, als2);
    k_prepatt<<<gW1, 256, 0, stream>>>(x, emb, a1ps, a1pd, xc16, ntypes, als1, ald1);

    // CSR build: bucket scatter -> per-bucket counting sort (self-computed base)
    k_bucket<<<(ETOT + CHUNK - 1) / CHUNK, 256, 0, stream>>>(ei, bcur, bbuf);
    k_csrb  <<<NBUCK, 256, 0, stream>>>(bcur, bbuf, rowptr, csr);

    // Layer 1 (linearity-swapped; scores from k_prepatt; alpha fused in agg)
    k_aggx<<<gW1, 256, 0, stream>>>(rowptr, csr, als1, ald1, xc16, h16 /*xagg*/);
    k_gemm1h<<<dim3(RB, 4), 256, 0, stream>>>(h16 /*xagg*/, Wt1, b1, z16, NN);

    // Layer 2 (att fused into 128x128 GEMM epilogue; alpha fused in agg)
    k_gemmw<256, 256, 2><<<dim3(RB2, 2), 256, 0, stream>>>(z16, Wt2, h16, NN, as2, ad2, als2, ald2);
    k_agg2f<<<gW1, 256, 0, stream>>>(rowptr, csr, als2, ald2, h16, b2, z16);

    // Layer 3 (att fused into 128x128 GEMM epilogue; alpha fused in agg)
    k_gemmw<256, 128, 1><<<dim3(RB2, 1), 256, 0, stream>>>(z16, Wt3, h16, NN, as3, ad3, als3, ald3);
    k_agg3<<<gW1, 256, 0, stream>>>(rowptr, csr, als3, ald3, h16, b3, z16);

    // Decoder (MFMA)
    k_decm<<<(ELN + 63) / 64, 256, 0, stream>>>(z16, eli, ntypes, Wtl, bl1, Wl2, bl2, tb, out);
}